// Round 6
// baseline (280.295 us; speedup 1.0000x reference)
//
#include <hip/hip_runtime.h>
#include <math.h>

#define N_NODES 50000
#define F_IN 256
#define HID 128
#define C_OUT 40
#define BINS ((N_NODES + 255) / 256)   // 196 buckets of 256 nodes

typedef __attribute__((ext_vector_type(8))) short short8;
typedef __attribute__((ext_vector_type(4))) float floatx4;
typedef __attribute__((ext_vector_type(2))) float floatx2;

__device__ __forceinline__ unsigned short f2bf(float f) {
    unsigned int u = __float_as_uint(f);
    unsigned int r = (u + 0x7FFFu + ((u >> 16) & 1u)) >> 16;
    return (unsigned short)r;
}
__device__ __forceinline__ unsigned int pack2bf(float a, float b) {
    return (unsigned int)f2bf(a) | ((unsigned int)f2bf(b) << 16);
}
__device__ __forceinline__ float bf_lo(unsigned int u) { return __uint_as_float(u << 16); }
__device__ __forceinline__ float bf_hi(unsigned int u) { return __uint_as_float(u & 0xFFFF0000u); }

// ---------------- phase 1: bucket histogram ----------------
__global__ void k_hist(const int* __restrict__ dst, int E, int* __restrict__ binCount) {
    __shared__ int h[BINS];
    for (int i = threadIdx.x; i < BINS; i += 256) h[i] = 0;
    __syncthreads();
    for (int e = blockIdx.x * 256 + threadIdx.x; e < E; e += gridDim.x * 256)
        atomicAdd(&h[dst[e] >> 8], 1);
    __syncthreads();
    for (int i = threadIdx.x; i < BINS; i += 256)
        if (h[i]) atomicAdd(&binCount[i], h[i]);
}

// ---------------- phase 2: scan buckets ----------------
__global__ void k_scan_bins(const int* __restrict__ binCount, int* __restrict__ bucketBase,
                            int* __restrict__ binCursor, int* __restrict__ offsets, int E) {
    __shared__ int sd[256];
    int t = threadIdx.x;
    int v = (t < BINS) ? binCount[t] : 0;
    sd[t] = v; __syncthreads();
    for (int off = 1; off < 256; off <<= 1) {
        int tmp = (t >= off) ? sd[t - off] : 0;
        __syncthreads();
        sd[t] += tmp;
        __syncthreads();
    }
    int ex = sd[t] - v;
    if (t < BINS) { bucketBase[t] = ex; binCursor[t] = ex; }
    if (t == 0) { bucketBase[BINS] = E; offsets[N_NODES] = E; }
}

// ---------------- phase 3: partition edges into buckets ----------------
#define PCHUNK 4096
#define PTHREADS 256
__launch_bounds__(PTHREADS)
__global__ void k_partition(const int* __restrict__ src, const int* __restrict__ dst, int E,
                            int* __restrict__ binCursor, unsigned int* __restrict__ packed) {
    __shared__ unsigned int lpack[PCHUNK];   // (local_dst<<16)|src
    __shared__ unsigned int lpos[PCHUNK];    // (rank<<8)|bin
    __shared__ int lcnt[BINS];
    __shared__ int lrun[BINS];
    int t = threadIdx.x;
    int base = blockIdx.x * PCHUNK;
    int n = E - base; if (n > PCHUNK) n = PCHUNK;
    for (int i = t; i < BINS; i += PTHREADS) lcnt[i] = 0;
    __syncthreads();
    for (int i = t; i < n; i += PTHREADS) {
        int d = dst[base + i], s = src[base + i];
        int bin = d >> 8;
        unsigned int r = (unsigned int)atomicAdd(&lcnt[bin], 1);
        lpack[i] = ((unsigned int)(d & 255) << 16) | (unsigned int)s;
        lpos[i] = (r << 8) | (unsigned int)bin;
    }
    __syncthreads();
    if (t < BINS && lcnt[t] > 0) lrun[t] = atomicAdd(&binCursor[t], lcnt[t]);
    __syncthreads();
    for (int i = t; i < n; i += PTHREADS) {
        unsigned int p = lpos[i];
        int bin = p & 255;
        unsigned int r = p >> 8;
        packed[(size_t)lrun[bin] + r] = lpack[i];
    }
}

// ---------------- phase 4: per-bucket CSR (offsets, dinv, col) ----------------
__launch_bounds__(256)
__global__ void k_bucket_csr(const unsigned int* __restrict__ packed, const int* __restrict__ bucketBase,
                             int* __restrict__ offsets, float* __restrict__ dinv,
                             unsigned short* __restrict__ col, int N) {
    __shared__ int lcnt[256];
    __shared__ int lscan[256];
    __shared__ int lofs[256];
    int b = blockIdx.x, t = threadIdx.x;
    int s = bucketBase[b], e = bucketBase[b + 1];
    lcnt[t] = 0;
    __syncthreads();
    for (int i = s + t; i < e; i += 256) atomicAdd(&lcnt[packed[i] >> 16], 1);
    __syncthreads();
    int v = lcnt[t];
    lscan[t] = v;
    __syncthreads();
    for (int off = 1; off < 256; off <<= 1) {
        int tmp = (t >= off) ? lscan[t - off] : 0;
        __syncthreads();
        lscan[t] += tmp;
        __syncthreads();
    }
    int ex = lscan[t] - v;
    int node = b * 256 + t;
    if (node < N) {
        offsets[node] = s + ex;
        dinv[node] = rsqrtf((float)(v + 1));   // deg incl. self-loop
    }
    __syncthreads();
    lofs[t] = ex;
    lcnt[t] = 0;
    __syncthreads();
    for (int i = s + t; i < e; i += 256) {
        unsigned int p = packed[i];
        int ld = (int)(p >> 16);
        int r = atomicAdd(&lcnt[ld], 1);
        col[(size_t)s + lofs[ld] + r] = (unsigned short)(p & 0xFFFFu);
    }
}

// ---------------- cast W1 -> bf16 transposed [HID][F_IN] ----------------
__global__ void k_castW1(const float* __restrict__ W1, unsigned short* __restrict__ W1bT) {
    int i = blockIdx.x * 256 + threadIdx.x;   // i = n*256 + k
    if (i < HID * F_IN) {
        int n = i >> 8, k = i & 255;
        W1bT[i] = f2bf(W1[(size_t)k * HID + n]);
    }
}

// ---------------- GEMM1 (MFMA bf16): y1f = fp8((x @ W1) * dinv[row]) ----------------
__launch_bounds__(256)
__global__ void k_gemm1(const float* __restrict__ A, const unsigned short* __restrict__ BT,
                        const float* __restrict__ dinv, unsigned short* __restrict__ Yf, int M) {
    __shared__ __align__(16) unsigned short As[64][72];    // 64 rows x 64 bf16 (+8 pad)
    __shared__ __align__(16) unsigned short Bs[128][72];   // 128 n-rows x 64 bf16 (+8 pad)
    int t = threadIdx.x;
    int w = t >> 6, lane = t & 63;
    int q = lane >> 4, m = lane & 15;
    int row0 = blockIdx.x * 64;

    floatx4 acc[4][2];
#pragma unroll
    for (int rt = 0; rt < 4; rt++)
#pragma unroll
        for (int ct = 0; ct < 2; ct++) acc[rt][ct] = (floatx4){0.f, 0.f, 0.f, 0.f};

    int ar = t >> 2;
    int ac = (t & 3) * 16;
    int brow = t >> 1;
    int bh = (t & 1) * 32;

    for (int k0 = 0; k0 < F_IN; k0 += 64) {
        {
            int grow = row0 + ar;
            float4 v0, v1, v2, v3;
            if (grow < M) {
                const float* sp = A + (size_t)grow * F_IN + k0 + ac;
                v0 = *(const float4*)(sp);     v1 = *(const float4*)(sp + 4);
                v2 = *(const float4*)(sp + 8); v3 = *(const float4*)(sp + 12);
            } else {
                v0 = v1 = v2 = v3 = make_float4(0.f, 0.f, 0.f, 0.f);
            }
            uint4 u0, u1;
            u0.x = pack2bf(v0.x, v0.y); u0.y = pack2bf(v0.z, v0.w);
            u0.z = pack2bf(v1.x, v1.y); u0.w = pack2bf(v1.z, v1.w);
            u1.x = pack2bf(v2.x, v2.y); u1.y = pack2bf(v2.z, v2.w);
            u1.z = pack2bf(v3.x, v3.y); u1.w = pack2bf(v3.z, v3.w);
            *(uint4*)&As[ar][ac] = u0;
            *(uint4*)&As[ar][ac + 8] = u1;
        }
        {
            const unsigned short* sp = BT + (size_t)brow * F_IN + k0 + bh;
            uint4 b0 = *(const uint4*)(sp);
            uint4 b1 = *(const uint4*)(sp + 8);
            uint4 b2 = *(const uint4*)(sp + 16);
            uint4 b3 = *(const uint4*)(sp + 24);
            *(uint4*)&Bs[brow][bh] = b0;
            *(uint4*)&Bs[brow][bh + 8] = b1;
            *(uint4*)&Bs[brow][bh + 16] = b2;
            *(uint4*)&Bs[brow][bh + 24] = b3;
        }
        __syncthreads();
#pragma unroll
        for (int kc = 0; kc < 64; kc += 32) {
            short8 af[4];
#pragma unroll
            for (int rt = 0; rt < 4; rt++)
                af[rt] = *(const short8*)&As[rt * 16 + m][kc + q * 8];
#pragma unroll
            for (int ct = 0; ct < 2; ct++) {
                short8 bfr = *(const short8*)&Bs[w * 32 + ct * 16 + m][kc + q * 8];
#pragma unroll
                for (int rt = 0; rt < 4; rt++)
                    acc[rt][ct] = __builtin_amdgcn_mfma_f32_16x16x32_bf16(af[rt], bfr, acc[rt][ct], 0, 0, 0);
            }
        }
        __syncthreads();
    }
#pragma unroll
    for (int rt = 0; rt < 4; rt++) {
#pragma unroll
        for (int r = 0; r < 4; r++) {
            int grow = row0 + rt * 16 + q * 4 + r;
            if (grow < M) {
                float d = dinv[grow];
                int pk = __builtin_amdgcn_cvt_pk_fp8_f32(acc[rt][0][r] * d, acc[rt][1][r] * d, 0, false);
                Yf[(size_t)grow * 64 + w * 16 + m] = (unsigned short)pk;
            }
        }
    }
}

// ---------------- GEMM2: y2b = bf16((hid @ W2) * dinv[row]) ----------------
__launch_bounds__(256)
__global__ void k_gemm2(const float* __restrict__ A, const float* __restrict__ B,
                        const float* __restrict__ dinv, unsigned short* __restrict__ Yb, int M) {
    const int BM = 128, BK = 32, TM = 4, TN = 5;
    __shared__ float As[BM][BK + 4];
    __shared__ float Bs[BK][C_OUT];
    int t = threadIdx.x;
    int tx = t & 7;
    int ty = t >> 3;
    int row0 = blockIdx.x * BM;
    float acc[TM][TN];
#pragma unroll
    for (int i = 0; i < TM; i++)
#pragma unroll
        for (int j = 0; j < TN; j++) acc[i][j] = 0.f;

    int am = t >> 1;

    for (int k0 = 0; k0 < HID; k0 += BK) {
#pragma unroll
        for (int h = 0; h < 4; h++) {
            int kq = (t & 1) + h * 2;
            int row = row0 + am;
            float4 v = (row < M) ? *(const float4*)(A + (size_t)row * HID + k0 + kq * 4)
                                 : make_float4(0.f, 0.f, 0.f, 0.f);
            As[am][kq * 4 + 0] = v.x; As[am][kq * 4 + 1] = v.y;
            As[am][kq * 4 + 2] = v.z; As[am][kq * 4 + 3] = v.w;
        }
        for (int l = t; l < BK * (C_OUT / 4); l += 256) {
            int kk = l / (C_OUT / 4), qq = l % (C_OUT / 4);
            *(float4*)&Bs[kk][qq * 4] = *(const float4*)(B + (size_t)(k0 + kk) * C_OUT + qq * 4);
        }
        __syncthreads();
#pragma unroll
        for (int kk = 0; kk < BK; kk++) {
            float a[TM], bv[TN];
#pragma unroll
            for (int i = 0; i < TM; i++) a[i] = As[ty * TM + i][kk];
#pragma unroll
            for (int j = 0; j < TN; j++) bv[j] = Bs[kk][tx * TN + j];
#pragma unroll
            for (int i = 0; i < TM; i++)
#pragma unroll
                for (int j = 0; j < TN; j++) acc[i][j] = fmaf(a[i], bv[j], acc[i][j]);
        }
        __syncthreads();
    }
#pragma unroll
    for (int i = 0; i < TM; i++) {
        int row = row0 + ty * TM + i;
        if (row < M) {
            float d = dinv[row];
#pragma unroll
            for (int j = 0; j < TN; j++)
                Yb[(size_t)row * C_OUT + tx * TN + j] = f2bf(acc[i][j] * d);
        }
    }
}

// ---------------- agg1: 16 lanes/edge (uint2 fp8 = 8 features), 4 edge groups ----------------
// y1f row = 64 ushorts (128 B). Lane lg covers ushorts lg*4..lg*4+3.
// ushort p -> features f_lo = (p>>4)*32 + (p&15), f_hi = f_lo + 16.
// Edge ids staged via LDS 4x16 transpose (edge q -> slot (q&3)*16+(q>>2)); group g
// reads its 16 edge ids contiguously. Full blocks 4-deep; boundary block now also
// batched 4-deep (load-all, then zero-if-invalid + accumulate: value-identical to
// the proven round-2 kernel).
__device__ __forceinline__ void fp8acc8(uint2 v, floatx2* a) {
    a[0] += __builtin_amdgcn_cvt_pk_f32_fp8(v.x, false);
    a[1] += __builtin_amdgcn_cvt_pk_f32_fp8(v.x, true);
    a[2] += __builtin_amdgcn_cvt_pk_f32_fp8(v.y, false);
    a[3] += __builtin_amdgcn_cvt_pk_f32_fp8(v.y, true);
}

__launch_bounds__(256)
__global__ void k_agg1(const uint2* __restrict__ y1p, const unsigned short* __restrict__ col,
                       const int* __restrict__ offsets, const float* __restrict__ dinv,
                       const float* __restrict__ b1, float* __restrict__ hid, int N) {
    __shared__ __align__(16) unsigned short jT[4][64];   // per-wave transposed col window
    int lane = threadIdx.x & 63;
    int w = threadIdx.x >> 6;
    int node = blockIdx.x * 4 + w;
    if (node >= N) return;
    int g = lane >> 4;      // edge group 0..3
    int lg = lane & 15;     // 16 lanes x uint2 = 128 B row
    int s = offsets[node], e = offsets[node + 1];

    floatx2 acc2[4];
#pragma unroll
    for (int i = 0; i < 4; i++) acc2[i] = (floatx2){0.f, 0.f};
    if (g == 0) fp8acc8(y1p[(size_t)node * 16 + lg], acc2);   // self-loop

    for (int t0 = s; t0 < e; t0 += 64) {
        int cnt = e - t0; if (cnt > 64) cnt = 64;
        // stage col window, transposed: edge q -> LDS slot (q&3)*16 + (q>>2),
        // so group g reads its 16 edge ids (q = p*4+g, p=0..15) contiguously.
        unsigned short jv = (lane < cnt) ? col[t0 + lane] : (unsigned short)0;
        jT[w][(lane & 3) * 16 + (lane >> 2)] = jv;
        uint4 c0 = *(const uint4*)&jT[w][g * 16];        // p = 0..7
        uint4 c1 = *(const uint4*)&jT[w][g * 16 + 8];    // p = 8..15
        unsigned int cw[8] = {c0.x, c0.y, c0.z, c0.w, c1.x, c1.y, c1.z, c1.w};
        int cg = cnt - g;   // pass p valid iff p*4 < cg

#pragma unroll
        for (int pb = 0; pb < 4; ++pb) {
            if (pb * 16 >= cnt) break;               // uniform: no group has edges left
            if (pb * 16 + 16 <= cnt) {               // uniform: all 4 passes full
                uint2 u[4];
#pragma unroll
                for (int qq = 0; qq < 4; ++qq) {
                    int p = pb * 4 + qq;
                    unsigned int word = cw[p >> 1];
                    int j = (p & 1) ? (int)(word >> 16) : (int)(word & 0xFFFFu);
                    u[qq] = y1p[(size_t)j * 16 + lg];
                }
#pragma unroll
                for (int qq = 0; qq < 4; ++qq) fp8acc8(u[qq], acc2);
            } else {                                  // boundary block: batched issue/consume
                uint2 u[4];
#pragma unroll
                for (int qq = 0; qq < 4; ++qq) {
                    int p = pb * 4 + qq;
                    if (p * 4 >= cnt) break;         // uniform
                    unsigned int word = cw[p >> 1];
                    int j = (p & 1) ? (int)(word >> 16) : (int)(word & 0xFFFFu);
                    u[qq] = y1p[(size_t)j * 16 + lg];
                }
#pragma unroll
                for (int qq = 0; qq < 4; ++qq) {
                    int p = pb * 4 + qq;
                    if (p * 4 >= cnt) break;         // uniform
                    uint2 v = u[qq];
                    if (p * 4 >= cg) { v.x = 0u; v.y = 0u; }   // invalid lane-group: add 0
                    fp8acc8(v, acc2);
                }
            }
        }
    }
    // reduce across 4 edge groups (lanes at stride 16)
#pragma unroll
    for (int k = 0; k < 4; k++) {
        acc2[k][0] += __shfl(acc2[k][0], lane + 32);
        acc2[k][1] += __shfl(acc2[k][1], lane + 32);
    }
#pragma unroll
    for (int k = 0; k < 4; k++) {
        acc2[k][0] += __shfl(acc2[k][0], lane + 16);
        acc2[k][1] += __shfl(acc2[k][1], lane + 16);
    }
    if (g == 0) {
        float d = dinv[node];
        int base = (lg >> 2) * 32 + (lg & 3) * 4;
        float4 bL = *(const float4*)(b1 + base);
        float4 bH = *(const float4*)(b1 + base + 16);
        float4 oL, oH;
        oL.x = fmaxf(fmaf(d, acc2[0][0], bL.x), 0.f);
        oL.y = fmaxf(fmaf(d, acc2[1][0], bL.y), 0.f);
        oL.z = fmaxf(fmaf(d, acc2[2][0], bL.z), 0.f);
        oL.w = fmaxf(fmaf(d, acc2[3][0], bL.w), 0.f);
        oH.x = fmaxf(fmaf(d, acc2[0][1], bH.x), 0.f);
        oH.y = fmaxf(fmaf(d, acc2[1][1], bH.y), 0.f);
        oH.z = fmaxf(fmaf(d, acc2[2][1], bH.z), 0.f);
        oH.w = fmaxf(fmaf(d, acc2[3][1], bH.w), 0.f);
        float* op = hid + (size_t)node * HID + base;
        *(float4*)(op) = oL;
        *(float4*)(op + 16) = oH;
    }
}

// ---------------- agg2: 10 lanes/edge (uint2), 6 edges/pass + softmax ----------------
// Proven shuffle indexing; gathers now issued up to 10-deep (issue/consume split
// with validity bitmask) — loads, masks, and accumulation order identical to the
// proven round-2 kernel.
__launch_bounds__(256)
__global__ void k_agg2(const uint2* __restrict__ y2b2, const unsigned short* __restrict__ col,
                       const int* __restrict__ offsets, const float* __restrict__ dinv,
                       const float* __restrict__ b2, float* __restrict__ x2out,
                       float* __restrict__ logp, int N) {
    int lane = threadIdx.x & 63;
    int w = threadIdx.x >> 6;
    int node = blockIdx.x * 4 + w;
    if (node >= N) return;
    int g = lane / 10;
    int lg = lane - g * 10;
    bool lact = lane < 60;
    int s = offsets[node], e = offsets[node + 1];

    float a0, a1, a2, a3;
    if (lact && g == 0) {
        uint2 sv = y2b2[(size_t)node * 10 + lg];
        a0 = bf_lo(sv.x); a1 = bf_hi(sv.x); a2 = bf_lo(sv.y); a3 = bf_hi(sv.y);
    } else { a0 = a1 = a2 = a3 = 0.f; }

    for (int t0 = s; t0 < e; t0 += 60) {
        int cnt = e - t0; if (cnt > 60) cnt = 60;
        int jreg = (lane < cnt) ? (int)col[t0 + lane] : 0;
        uint2 u[10];
        unsigned int vm = 0;
#pragma unroll
        for (int p = 0; p < 10; ++p) {       // issue (uniform break; loads guarded as before)
            if (p * 6 >= cnt) break;
            int idx = p * 6 + g;
            bool valid = lact && idx < cnt;
            int j = __shfl(jreg, idx);       // garbage when invalid; never consumed
            if (valid) { u[p] = y2b2[(size_t)j * 10 + lg]; vm |= (1u << p); }
        }
#pragma unroll
        for (int p = 0; p < 10; ++p) {       // consume
            if (p * 6 >= cnt) break;         // uniform
            if (vm & (1u << p)) {
                uint2 v = u[p];
                a0 += bf_lo(v.x); a1 += bf_hi(v.x);
                a2 += bf_lo(v.y); a3 += bf_hi(v.y);
            }
        }
    }
    a0 += __shfl(a0, lane + 30); a1 += __shfl(a1, lane + 30);
    a2 += __shfl(a2, lane + 30); a3 += __shfl(a3, lane + 30);
    float r0 = a0 + __shfl(a0, lane + 10) + __shfl(a0, lane + 20);
    float r1 = a1 + __shfl(a1, lane + 10) + __shfl(a1, lane + 20);
    float r2 = a2 + __shfl(a2, lane + 10) + __shfl(a2, lane + 20);
    float r3 = a3 + __shfl(a3, lane + 10) + __shfl(a3, lane + 20);

    float x0, x1, x2v, x3;
    if (lane < 10) {
        float d = dinv[node];
        float4 bb = ((const float4*)b2)[lg];
        x0 = fmaf(d, r0, bb.x); x1 = fmaf(d, r1, bb.y);
        x2v = fmaf(d, r2, bb.z); x3 = fmaf(d, r3, bb.w);
        float4* xo = (float4*)(x2out + (size_t)node * C_OUT);
        xo[lg] = make_float4(x0, x1, x2v, x3);
    } else { x0 = x1 = x2v = x3 = -INFINITY; }

    float m = fmaxf(fmaxf(x0, x1), fmaxf(x2v, x3));
#pragma unroll
    for (int off = 1; off < 16; off <<= 1) m = fmaxf(m, __shfl_xor(m, off));
    float sum = (lane < 10) ? (expf(x0 - m) + expf(x1 - m) + expf(x2v - m) + expf(x3 - m)) : 0.f;
#pragma unroll
    for (int off = 1; off < 16; off <<= 1) sum += __shfl_xor(sum, off);
    if (lane < 10) {
        float lse = m + logf(sum);
        float4* lo = (float4*)(logp + (size_t)node * C_OUT);
        lo[lg] = make_float4(x0 - lse, x1 - lse, x2v - lse, x3 - lse);
    }
}

// ---------------- launcher ----------------
extern "C" void kernel_launch(void* const* d_in, const int* in_sizes, int n_in,
                              void* d_out, int out_size, void* d_ws, size_t ws_size,
                              hipStream_t stream) {
    const float* x  = (const float*)d_in[0];
    const int*   ei = (const int*)d_in[1];
    const float* W1 = (const float*)d_in[2];
    const float* b1 = (const float*)d_in[3];
    const float* W2 = (const float*)d_in[4];
    const float* b2 = (const float*)d_in[5];
    const int N = N_NODES;
    const int E = in_sizes[1] / 2;
    const int* src = ei;
    const int* dst = ei + E;

    float* out_hid  = (float*)d_out;                       // N*128
    float* out_x2   = out_hid + (size_t)N * HID;           // N*40
    float* out_logp = out_x2 + (size_t)N * C_OUT;          // N*40

    char* p = (char*)d_ws;
    auto alloc = [&](size_t bytes) { void* r = (void*)p; p += (bytes + 255) & ~255ull; return r; };
    int*   binCount   = (int*)alloc((size_t)BINS * 4);
    int*   bucketBase = (int*)alloc((size_t)(BINS + 1) * 4);
    int*   binCursor  = (int*)alloc((size_t)BINS * 4);
    int*   offsets    = (int*)alloc((size_t)(N + 1) * 4);
    float* dinv       = (float*)alloc((size_t)N * 4);
    unsigned int*   packed = (unsigned int*)alloc((size_t)E * 4);
    unsigned short* col    = (unsigned short*)alloc((size_t)(E + 64) * 2);
    unsigned short* y1f    = (unsigned short*)alloc((size_t)N * 64 * 2);        // fp8 pairs
    unsigned short* y2b    = (unsigned short*)alloc((size_t)N * C_OUT * 2);     // bf16
    unsigned short* W1bT   = (unsigned short*)alloc((size_t)HID * F_IN * 2);    // bf16 [N][K]

    hipMemsetAsync(binCount, 0, (size_t)BINS * 4, stream);
    k_hist<<<512, 256, 0, stream>>>(dst, E, binCount);
    k_scan_bins<<<1, 256, 0, stream>>>(binCount, bucketBase, binCursor, offsets, E);
    k_partition<<<(E + PCHUNK - 1) / PCHUNK, PTHREADS, 0, stream>>>(src, dst, E, binCursor, packed);
    k_bucket_csr<<<BINS, 256, 0, stream>>>(packed, bucketBase, offsets, dinv, col, N);
    k_castW1<<<(HID * F_IN + 255) / 256, 256, 0, stream>>>(W1, W1bT);
    k_gemm1<<<(N + 63) / 64, 256, 0, stream>>>(x, W1bT, dinv, y1f, N);
    k_agg1<<<(N + 3) / 4, 256, 0, stream>>>((const uint2*)y1f, col, offsets, dinv, b1, out_hid, N);
    k_gemm2<<<(N + 127) / 128, 256, 0, stream>>>(out_hid, W2, dinv, y2b, N);
    k_agg2<<<(N + 3) / 4, 256, 0, stream>>>((const uint2*)y2b, col, offsets, dinv, b2, out_x2, out_logp, N);
}

// Round 7
// 246.780 us; speedup vs baseline: 1.1358x; 1.1358x over previous
//
#include <hip/hip_runtime.h>
#include <math.h>

#define N_NODES 50000
#define F_IN 256
#define HID 128
#define C_OUT 40
#define BINS ((N_NODES + 255) / 256)   // 196 buckets of 256 nodes

typedef __attribute__((ext_vector_type(8))) short short8;
typedef __attribute__((ext_vector_type(4))) float floatx4;
typedef __attribute__((ext_vector_type(2))) float floatx2;

__device__ __forceinline__ unsigned short f2bf(float f) {
    unsigned int u = __float_as_uint(f);
    unsigned int r = (u + 0x7FFFu + ((u >> 16) & 1u)) >> 16;
    return (unsigned short)r;
}
__device__ __forceinline__ unsigned int pack2bf(float a, float b) {
    return (unsigned int)f2bf(a) | ((unsigned int)f2bf(b) << 16);
}
__device__ __forceinline__ float bf_lo(unsigned int u) { return __uint_as_float(u << 16); }
__device__ __forceinline__ float bf_hi(unsigned int u) { return __uint_as_float(u & 0xFFFF0000u); }

// ---------------- phase 1: bucket histogram ----------------
__global__ void k_hist(const int* __restrict__ dst, int E, int* __restrict__ binCount) {
    __shared__ int h[BINS];
    for (int i = threadIdx.x; i < BINS; i += 256) h[i] = 0;
    __syncthreads();
    for (int e = blockIdx.x * 256 + threadIdx.x; e < E; e += gridDim.x * 256)
        atomicAdd(&h[dst[e] >> 8], 1);
    __syncthreads();
    for (int i = threadIdx.x; i < BINS; i += 256)
        if (h[i]) atomicAdd(&binCount[i], h[i]);
}

// ---------------- phase 2: scan buckets ----------------
__global__ void k_scan_bins(const int* __restrict__ binCount, int* __restrict__ bucketBase,
                            int* __restrict__ binCursor, int* __restrict__ offsets, int E) {
    __shared__ int sd[256];
    int t = threadIdx.x;
    int v = (t < BINS) ? binCount[t] : 0;
    sd[t] = v; __syncthreads();
    for (int off = 1; off < 256; off <<= 1) {
        int tmp = (t >= off) ? sd[t - off] : 0;
        __syncthreads();
        sd[t] += tmp;
        __syncthreads();
    }
    int ex = sd[t] - v;
    if (t < BINS) { bucketBase[t] = ex; binCursor[t] = ex; }
    if (t == 0) { bucketBase[BINS] = E; offsets[N_NODES] = E; }
}

// ---------------- phase 3: partition edges into buckets ----------------
#define PCHUNK 4096
#define PTHREADS 256
__launch_bounds__(PTHREADS)
__global__ void k_partition(const int* __restrict__ src, const int* __restrict__ dst, int E,
                            int* __restrict__ binCursor, unsigned int* __restrict__ packed) {
    __shared__ unsigned int lpack[PCHUNK];   // (local_dst<<16)|src
    __shared__ unsigned int lpos[PCHUNK];    // (rank<<8)|bin
    __shared__ int lcnt[BINS];
    __shared__ int lrun[BINS];
    int t = threadIdx.x;
    int base = blockIdx.x * PCHUNK;
    int n = E - base; if (n > PCHUNK) n = PCHUNK;
    for (int i = t; i < BINS; i += PTHREADS) lcnt[i] = 0;
    __syncthreads();
    for (int i = t; i < n; i += PTHREADS) {
        int d = dst[base + i], s = src[base + i];
        int bin = d >> 8;
        unsigned int r = (unsigned int)atomicAdd(&lcnt[bin], 1);
        lpack[i] = ((unsigned int)(d & 255) << 16) | (unsigned int)s;
        lpos[i] = (r << 8) | (unsigned int)bin;
    }
    __syncthreads();
    if (t < BINS && lcnt[t] > 0) lrun[t] = atomicAdd(&binCursor[t], lcnt[t]);
    __syncthreads();
    for (int i = t; i < n; i += PTHREADS) {
        unsigned int p = lpos[i];
        int bin = p & 255;
        unsigned int r = p >> 8;
        packed[(size_t)lrun[bin] + r] = lpack[i];
    }
}

// ---------------- phase 4: per-bucket CSR (offsets, dinv, col) ----------------
__launch_bounds__(256)
__global__ void k_bucket_csr(const unsigned int* __restrict__ packed, const int* __restrict__ bucketBase,
                             int* __restrict__ offsets, float* __restrict__ dinv,
                             unsigned short* __restrict__ col, int N) {
    __shared__ int lcnt[256];
    __shared__ int lscan[256];
    __shared__ int lofs[256];
    int b = blockIdx.x, t = threadIdx.x;
    int s = bucketBase[b], e = bucketBase[b + 1];
    lcnt[t] = 0;
    __syncthreads();
    for (int i = s + t; i < e; i += 256) atomicAdd(&lcnt[packed[i] >> 16], 1);
    __syncthreads();
    int v = lcnt[t];
    lscan[t] = v;
    __syncthreads();
    for (int off = 1; off < 256; off <<= 1) {
        int tmp = (t >= off) ? lscan[t - off] : 0;
        __syncthreads();
        lscan[t] += tmp;
        __syncthreads();
    }
    int ex = lscan[t] - v;
    int node = b * 256 + t;
    if (node < N) {
        offsets[node] = s + ex;
        dinv[node] = rsqrtf((float)(v + 1));   // deg incl. self-loop
    }
    __syncthreads();
    lofs[t] = ex;
    lcnt[t] = 0;
    __syncthreads();
    for (int i = s + t; i < e; i += 256) {
        unsigned int p = packed[i];
        int ld = (int)(p >> 16);
        int r = atomicAdd(&lcnt[ld], 1);
        col[(size_t)s + lofs[ld] + r] = (unsigned short)(p & 0xFFFFu);
    }
}

// ---------------- cast W1 -> bf16 transposed [HID][F_IN] ----------------
__global__ void k_castW1(const float* __restrict__ W1, unsigned short* __restrict__ W1bT) {
    int i = blockIdx.x * 256 + threadIdx.x;   // i = n*256 + k
    if (i < HID * F_IN) {
        int n = i >> 8, k = i & 255;
        W1bT[i] = f2bf(W1[(size_t)k * HID + n]);
    }
}

// ---------------- GEMM1 (MFMA bf16): y1f = fp8((x @ W1) * dinv[row]) ----------------
__launch_bounds__(256)
__global__ void k_gemm1(const float* __restrict__ A, const unsigned short* __restrict__ BT,
                        const float* __restrict__ dinv, unsigned short* __restrict__ Yf, int M) {
    __shared__ __align__(16) unsigned short As[64][72];    // 64 rows x 64 bf16 (+8 pad)
    __shared__ __align__(16) unsigned short Bs[128][72];   // 128 n-rows x 64 bf16 (+8 pad)
    int t = threadIdx.x;
    int w = t >> 6, lane = t & 63;
    int q = lane >> 4, m = lane & 15;
    int row0 = blockIdx.x * 64;

    floatx4 acc[4][2];
#pragma unroll
    for (int rt = 0; rt < 4; rt++)
#pragma unroll
        for (int ct = 0; ct < 2; ct++) acc[rt][ct] = (floatx4){0.f, 0.f, 0.f, 0.f};

    int ar = t >> 2;
    int ac = (t & 3) * 16;
    int brow = t >> 1;
    int bh = (t & 1) * 32;

    for (int k0 = 0; k0 < F_IN; k0 += 64) {
        {
            int grow = row0 + ar;
            float4 v0, v1, v2, v3;
            if (grow < M) {
                const float* sp = A + (size_t)grow * F_IN + k0 + ac;
                v0 = *(const float4*)(sp);     v1 = *(const float4*)(sp + 4);
                v2 = *(const float4*)(sp + 8); v3 = *(const float4*)(sp + 12);
            } else {
                v0 = v1 = v2 = v3 = make_float4(0.f, 0.f, 0.f, 0.f);
            }
            uint4 u0, u1;
            u0.x = pack2bf(v0.x, v0.y); u0.y = pack2bf(v0.z, v0.w);
            u0.z = pack2bf(v1.x, v1.y); u0.w = pack2bf(v1.z, v1.w);
            u1.x = pack2bf(v2.x, v2.y); u1.y = pack2bf(v2.z, v2.w);
            u1.z = pack2bf(v3.x, v3.y); u1.w = pack2bf(v3.z, v3.w);
            *(uint4*)&As[ar][ac] = u0;
            *(uint4*)&As[ar][ac + 8] = u1;
        }
        {
            const unsigned short* sp = BT + (size_t)brow * F_IN + k0 + bh;
            uint4 b0 = *(const uint4*)(sp);
            uint4 b1 = *(const uint4*)(sp + 8);
            uint4 b2 = *(const uint4*)(sp + 16);
            uint4 b3 = *(const uint4*)(sp + 24);
            *(uint4*)&Bs[brow][bh] = b0;
            *(uint4*)&Bs[brow][bh + 8] = b1;
            *(uint4*)&Bs[brow][bh + 16] = b2;
            *(uint4*)&Bs[brow][bh + 24] = b3;
        }
        __syncthreads();
#pragma unroll
        for (int kc = 0; kc < 64; kc += 32) {
            short8 af[4];
#pragma unroll
            for (int rt = 0; rt < 4; rt++)
                af[rt] = *(const short8*)&As[rt * 16 + m][kc + q * 8];
#pragma unroll
            for (int ct = 0; ct < 2; ct++) {
                short8 bfr = *(const short8*)&Bs[w * 32 + ct * 16 + m][kc + q * 8];
#pragma unroll
                for (int rt = 0; rt < 4; rt++)
                    acc[rt][ct] = __builtin_amdgcn_mfma_f32_16x16x32_bf16(af[rt], bfr, acc[rt][ct], 0, 0, 0);
            }
        }
        __syncthreads();
    }
#pragma unroll
    for (int rt = 0; rt < 4; rt++) {
#pragma unroll
        for (int r = 0; r < 4; r++) {
            int grow = row0 + rt * 16 + q * 4 + r;
            if (grow < M) {
                float d = dinv[grow];
                int pk = __builtin_amdgcn_cvt_pk_fp8_f32(acc[rt][0][r] * d, acc[rt][1][r] * d, 0, false);
                Yf[(size_t)grow * 64 + w * 16 + m] = (unsigned short)pk;
            }
        }
    }
}

// ---------------- GEMM2: y2b = bf16((hid @ W2) * dinv[row]) ----------------
__launch_bounds__(256)
__global__ void k_gemm2(const float* __restrict__ A, const float* __restrict__ B,
                        const float* __restrict__ dinv, unsigned short* __restrict__ Yb, int M) {
    const int BM = 128, BK = 32, TM = 4, TN = 5;
    __shared__ float As[BM][BK + 4];
    __shared__ float Bs[BK][C_OUT];
    int t = threadIdx.x;
    int tx = t & 7;
    int ty = t >> 3;
    int row0 = blockIdx.x * BM;
    float acc[TM][TN];
#pragma unroll
    for (int i = 0; i < TM; i++)
#pragma unroll
        for (int j = 0; j < TN; j++) acc[i][j] = 0.f;

    int am = t >> 1;

    for (int k0 = 0; k0 < HID; k0 += BK) {
#pragma unroll
        for (int h = 0; h < 4; h++) {
            int kq = (t & 1) + h * 2;
            int row = row0 + am;
            float4 v = (row < M) ? *(const float4*)(A + (size_t)row * HID + k0 + kq * 4)
                                 : make_float4(0.f, 0.f, 0.f, 0.f);
            As[am][kq * 4 + 0] = v.x; As[am][kq * 4 + 1] = v.y;
            As[am][kq * 4 + 2] = v.z; As[am][kq * 4 + 3] = v.w;
        }
        for (int l = t; l < BK * (C_OUT / 4); l += 256) {
            int kk = l / (C_OUT / 4), qq = l % (C_OUT / 4);
            *(float4*)&Bs[kk][qq * 4] = *(const float4*)(B + (size_t)(k0 + kk) * C_OUT + qq * 4);
        }
        __syncthreads();
#pragma unroll
        for (int kk = 0; kk < BK; kk++) {
            float a[TM], bv[TN];
#pragma unroll
            for (int i = 0; i < TM; i++) a[i] = As[ty * TM + i][kk];
#pragma unroll
            for (int j = 0; j < TN; j++) bv[j] = Bs[kk][tx * TN + j];
#pragma unroll
            for (int i = 0; i < TM; i++)
#pragma unroll
                for (int j = 0; j < TN; j++) acc[i][j] = fmaf(a[i], bv[j], acc[i][j]);
        }
        __syncthreads();
    }
#pragma unroll
    for (int i = 0; i < TM; i++) {
        int row = row0 + ty * TM + i;
        if (row < M) {
            float d = dinv[row];
#pragma unroll
            for (int j = 0; j < TN; j++)
                Yb[(size_t)row * C_OUT + tx * TN + j] = f2bf(acc[i][j] * d);
        }
    }
}

// ---------------- agg1: 16 lanes/edge (uint2 fp8 = 8 features), 4 edge groups ----------------
// y1f row = 64 ushorts (128 B). Lane lg covers ushorts lg*4..lg*4+3.
// ushort p -> features f_lo = (p>>4)*32 + (p&15), f_hi = f_lo + 16.
// Edge ids staged via LDS 4x16 transpose (edge q -> slot (q&3)*16+(q>>2)); group g
// reads its 16 edge ids contiguously. Gathers batched 4-deep (unconditional defs
// in the full path; bounded-break batched issue in the boundary path).
__device__ __forceinline__ void fp8acc8(uint2 v, floatx2* a) {
    a[0] += __builtin_amdgcn_cvt_pk_f32_fp8(v.x, false);
    a[1] += __builtin_amdgcn_cvt_pk_f32_fp8(v.x, true);
    a[2] += __builtin_amdgcn_cvt_pk_f32_fp8(v.y, false);
    a[3] += __builtin_amdgcn_cvt_pk_f32_fp8(v.y, true);
}

__launch_bounds__(256)
__global__ void k_agg1(const uint2* __restrict__ y1p, const unsigned short* __restrict__ col,
                       const int* __restrict__ offsets, const float* __restrict__ dinv,
                       const float* __restrict__ b1, float* __restrict__ hid, int N) {
    __shared__ __align__(16) unsigned short jT[4][64];   // per-wave transposed col window
    int lane = threadIdx.x & 63;
    int w = threadIdx.x >> 6;
    int node = blockIdx.x * 4 + w;
    if (node >= N) return;
    int g = lane >> 4;      // edge group 0..3
    int lg = lane & 15;     // 16 lanes x uint2 = 128 B row
    int s = offsets[node], e = offsets[node + 1];

    floatx2 acc2[4];
#pragma unroll
    for (int i = 0; i < 4; i++) acc2[i] = (floatx2){0.f, 0.f};
    if (g == 0) fp8acc8(y1p[(size_t)node * 16 + lg], acc2);   // self-loop

    for (int t0 = s; t0 < e; t0 += 64) {
        int cnt = e - t0; if (cnt > 64) cnt = 64;
        // stage col window, transposed: edge q -> LDS slot (q&3)*16 + (q>>2),
        // so group g reads its 16 edge ids (q = p*4+g, p=0..15) contiguously.
        unsigned short jv = (lane < cnt) ? col[t0 + lane] : (unsigned short)0;
        jT[w][(lane & 3) * 16 + (lane >> 2)] = jv;
        uint4 c0 = *(const uint4*)&jT[w][g * 16];        // p = 0..7
        uint4 c1 = *(const uint4*)&jT[w][g * 16 + 8];    // p = 8..15
        unsigned int cw[8] = {c0.x, c0.y, c0.z, c0.w, c1.x, c1.y, c1.z, c1.w};
        int cg = cnt - g;   // pass p valid iff p*4 < cg

#pragma unroll
        for (int pb = 0; pb < 4; ++pb) {
            if (pb * 16 >= cnt) break;               // uniform: no group has edges left
            if (pb * 16 + 16 <= cnt) {               // uniform: all 4 passes full
                uint2 u[4];
#pragma unroll
                for (int qq = 0; qq < 4; ++qq) {
                    int p = pb * 4 + qq;
                    unsigned int word = cw[p >> 1];
                    int j = (p & 1) ? (int)(word >> 16) : (int)(word & 0xFFFFu);
                    u[qq] = y1p[(size_t)j * 16 + lg];
                }
#pragma unroll
                for (int qq = 0; qq < 4; ++qq) fp8acc8(u[qq], acc2);
            } else {                                  // boundary block: batched issue/consume
                uint2 u[4];
#pragma unroll
                for (int qq = 0; qq < 4; ++qq) {
                    int p = pb * 4 + qq;
                    if (p * 4 >= cnt) break;         // uniform
                    unsigned int word = cw[p >> 1];
                    int j = (p & 1) ? (int)(word >> 16) : (int)(word & 0xFFFFu);
                    u[qq] = y1p[(size_t)j * 16 + lg];
                }
#pragma unroll
                for (int qq = 0; qq < 4; ++qq) {
                    int p = pb * 4 + qq;
                    if (p * 4 >= cnt) break;         // uniform
                    uint2 v = u[qq];
                    if (p * 4 >= cg) { v.x = 0u; v.y = 0u; }   // invalid lane-group: add 0
                    fp8acc8(v, acc2);
                }
            }
        }
    }
    // reduce across 4 edge groups (lanes at stride 16)
#pragma unroll
    for (int k = 0; k < 4; k++) {
        acc2[k][0] += __shfl(acc2[k][0], lane + 32);
        acc2[k][1] += __shfl(acc2[k][1], lane + 32);
    }
#pragma unroll
    for (int k = 0; k < 4; k++) {
        acc2[k][0] += __shfl(acc2[k][0], lane + 16);
        acc2[k][1] += __shfl(acc2[k][1], lane + 16);
    }
    if (g == 0) {
        float d = dinv[node];
        int base = (lg >> 2) * 32 + (lg & 3) * 4;
        float4 bL = *(const float4*)(b1 + base);
        float4 bH = *(const float4*)(b1 + base + 16);
        float4 oL, oH;
        oL.x = fmaxf(fmaf(d, acc2[0][0], bL.x), 0.f);
        oL.y = fmaxf(fmaf(d, acc2[1][0], bL.y), 0.f);
        oL.z = fmaxf(fmaf(d, acc2[2][0], bL.z), 0.f);
        oL.w = fmaxf(fmaf(d, acc2[3][0], bL.w), 0.f);
        oH.x = fmaxf(fmaf(d, acc2[0][1], bH.x), 0.f);
        oH.y = fmaxf(fmaf(d, acc2[1][1], bH.y), 0.f);
        oH.z = fmaxf(fmaf(d, acc2[2][1], bH.z), 0.f);
        oH.w = fmaxf(fmaf(d, acc2[3][1], bH.w), 0.f);
        float* op = hid + (size_t)node * HID + base;
        *(float4*)(op) = oL;
        *(float4*)(op + 16) = oH;
    }
}

// ---------------- agg2: 10 lanes/edge (uint2), 6 edges/pass + softmax ----------------
// Proven round-2 shuffle indexing and accumulation set/order; gathers issued up to
// 10-deep via NAMED scalar uint2s with unconditional defs inside wave-uniform
// guards (np > P), so SROA keeps them in VGPRs (round-6's conditional-def array
// was demoted to LDS by promote-alloca: 20 KB/block, 1.6M bank conflicts).
// Invalid lanes within an issued pass load a harmless in-bounds row (node id
// <= 49999); consume mask (P*6 < cg) selects exactly the round-2 add set.
__launch_bounds__(256)
__global__ void k_agg2(const uint2* __restrict__ y2b2, const unsigned short* __restrict__ col,
                       const int* __restrict__ offsets, const float* __restrict__ dinv,
                       const float* __restrict__ b2, float* __restrict__ x2out,
                       float* __restrict__ logp, int N) {
    int lane = threadIdx.x & 63;
    int w = threadIdx.x >> 6;
    int node = blockIdx.x * 4 + w;
    if (node >= N) return;
    int g = lane / 10;
    int lg = lane - g * 10;
    bool lact = lane < 60;
    int s = offsets[node], e = offsets[node + 1];

    float a0, a1, a2, a3;
    if (lact && g == 0) {
        uint2 sv = y2b2[(size_t)node * 10 + lg];
        a0 = bf_lo(sv.x); a1 = bf_hi(sv.x); a2 = bf_lo(sv.y); a3 = bf_hi(sv.y);
    } else { a0 = a1 = a2 = a3 = 0.f; }

    for (int t0 = s; t0 < e; t0 += 60) {
        int cnt = e - t0; if (cnt > 60) cnt = 60;
        int jreg = (lane < cnt) ? (int)col[t0 + lane] : 0;
        int np = (cnt + 5) / 6;          // uniform pass count, 1..10
        int cg = lact ? (cnt - g) : 0;   // pass P accumulates iff P*6 < cg
        uint2 u0, u1, u2, u3, u4, u5, u6, u7, u8, u9;
#define AG2_ISSUE(P, U) if (np > P) { int j = __shfl(jreg, P * 6 + g); U = y2b2[(size_t)j * 10 + lg]; }
        AG2_ISSUE(0, u0) AG2_ISSUE(1, u1) AG2_ISSUE(2, u2) AG2_ISSUE(3, u3) AG2_ISSUE(4, u4)
        AG2_ISSUE(5, u5) AG2_ISSUE(6, u6) AG2_ISSUE(7, u7) AG2_ISSUE(8, u8) AG2_ISSUE(9, u9)
#undef AG2_ISSUE
#define AG2_CONS(P, U) if (np > P) { if (P * 6 < cg) { \
            a0 += bf_lo(U.x); a1 += bf_hi(U.x); a2 += bf_lo(U.y); a3 += bf_hi(U.y); } }
        AG2_CONS(0, u0) AG2_CONS(1, u1) AG2_CONS(2, u2) AG2_CONS(3, u3) AG2_CONS(4, u4)
        AG2_CONS(5, u5) AG2_CONS(6, u6) AG2_CONS(7, u7) AG2_CONS(8, u8) AG2_CONS(9, u9)
#undef AG2_CONS
    }
    a0 += __shfl(a0, lane + 30); a1 += __shfl(a1, lane + 30);
    a2 += __shfl(a2, lane + 30); a3 += __shfl(a3, lane + 30);
    float r0 = a0 + __shfl(a0, lane + 10) + __shfl(a0, lane + 20);
    float r1 = a1 + __shfl(a1, lane + 10) + __shfl(a1, lane + 20);
    float r2 = a2 + __shfl(a2, lane + 10) + __shfl(a2, lane + 20);
    float r3 = a3 + __shfl(a3, lane + 10) + __shfl(a3, lane + 20);

    float x0, x1, x2v, x3;
    if (lane < 10) {
        float d = dinv[node];
        float4 bb = ((const float4*)b2)[lg];
        x0 = fmaf(d, r0, bb.x); x1 = fmaf(d, r1, bb.y);
        x2v = fmaf(d, r2, bb.z); x3 = fmaf(d, r3, bb.w);
        float4* xo = (float4*)(x2out + (size_t)node * C_OUT);
        xo[lg] = make_float4(x0, x1, x2v, x3);
    } else { x0 = x1 = x2v = x3 = -INFINITY; }

    float m = fmaxf(fmaxf(x0, x1), fmaxf(x2v, x3));
#pragma unroll
    for (int off = 1; off < 16; off <<= 1) m = fmaxf(m, __shfl_xor(m, off));
    float sum = (lane < 10) ? (expf(x0 - m) + expf(x1 - m) + expf(x2v - m) + expf(x3 - m)) : 0.f;
#pragma unroll
    for (int off = 1; off < 16; off <<= 1) sum += __shfl_xor(sum, off);
    if (lane < 10) {
        float lse = m + logf(sum);
        float4* lo = (float4*)(logp + (size_t)node * C_OUT);
        lo[lg] = make_float4(x0 - lse, x1 - lse, x2v - lse, x3 - lse);
    }
}

// ---------------- launcher ----------------
extern "C" void kernel_launch(void* const* d_in, const int* in_sizes, int n_in,
                              void* d_out, int out_size, void* d_ws, size_t ws_size,
                              hipStream_t stream) {
    const float* x  = (const float*)d_in[0];
    const int*   ei = (const int*)d_in[1];
    const float* W1 = (const float*)d_in[2];
    const float* b1 = (const float*)d_in[3];
    const float* W2 = (const float*)d_in[4];
    const float* b2 = (const float*)d_in[5];
    const int N = N_NODES;
    const int E = in_sizes[1] / 2;
    const int* src = ei;
    const int* dst = ei + E;

    float* out_hid  = (float*)d_out;                       // N*128
    float* out_x2   = out_hid + (size_t)N * HID;           // N*40
    float* out_logp = out_x2 + (size_t)N * C_OUT;          // N*40

    char* p = (char*)d_ws;
    auto alloc = [&](size_t bytes) { void* r = (void*)p; p += (bytes + 255) & ~255ull; return r; };
    int*   binCount   = (int*)alloc((size_t)BINS * 4);
    int*   bucketBase = (int*)alloc((size_t)(BINS + 1) * 4);
    int*   binCursor  = (int*)alloc((size_t)BINS * 4);
    int*   offsets    = (int*)alloc((size_t)(N + 1) * 4);
    float* dinv       = (float*)alloc((size_t)N * 4);
    unsigned int*   packed = (unsigned int*)alloc((size_t)E * 4);
    unsigned short* col    = (unsigned short*)alloc((size_t)(E + 64) * 2);
    unsigned short* y1f    = (unsigned short*)alloc((size_t)N * 64 * 2);        // fp8 pairs
    unsigned short* y2b    = (unsigned short*)alloc((size_t)N * C_OUT * 2);     // bf16
    unsigned short* W1bT   = (unsigned short*)alloc((size_t)HID * F_IN * 2);    // bf16 [N][K]

    hipMemsetAsync(binCount, 0, (size_t)BINS * 4, stream);
    k_hist<<<512, 256, 0, stream>>>(dst, E, binCount);
    k_scan_bins<<<1, 256, 0, stream>>>(binCount, bucketBase, binCursor, offsets, E);
    k_partition<<<(E + PCHUNK - 1) / PCHUNK, PTHREADS, 0, stream>>>(src, dst, E, binCursor, packed);
    k_bucket_csr<<<BINS, 256, 0, stream>>>(packed, bucketBase, offsets, dinv, col, N);
    k_castW1<<<(HID * F_IN + 255) / 256, 256, 0, stream>>>(W1, W1bT);
    k_gemm1<<<(N + 63) / 64, 256, 0, stream>>>(x, W1bT, dinv, y1f, N);
    k_agg1<<<(N + 3) / 4, 256, 0, stream>>>((const uint2*)y1f, col, offsets, dinv, b1, out_hid, N);
    k_gemm2<<<(N + 127) / 128, 256, 0, stream>>>(out_hid, W2, dinv, y2b, N);
    k_agg2<<<(N + 3) / 4, 256, 0, stream>>>((const uint2*)y2b, col, offsets, dinv, b2, out_x2, out_logp, N);
}

// Round 8
// 239.319 us; speedup vs baseline: 1.1712x; 1.0312x over previous
//
#include <hip/hip_runtime.h>
#include <math.h>

#define N_NODES 50000
#define F_IN 256
#define HID 128
#define C_OUT 40
#define BINS ((N_NODES + 255) / 256)   // 196 buckets of 256 nodes

typedef __attribute__((ext_vector_type(8))) short short8;
typedef __attribute__((ext_vector_type(4))) float floatx4;
typedef __attribute__((ext_vector_type(2))) float floatx2;

__device__ __forceinline__ unsigned short f2bf(float f) {
    unsigned int u = __float_as_uint(f);
    unsigned int r = (u + 0x7FFFu + ((u >> 16) & 1u)) >> 16;
    return (unsigned short)r;
}
__device__ __forceinline__ unsigned int pack2bf(float a, float b) {
    return (unsigned int)f2bf(a) | ((unsigned int)f2bf(b) << 16);
}
__device__ __forceinline__ float bf_lo(unsigned int u) { return __uint_as_float(u << 16); }
__device__ __forceinline__ float bf_hi(unsigned int u) { return __uint_as_float(u & 0xFFFF0000u); }

// ---------------- phase 1: bucket histogram ----------------
__global__ void k_hist(const int* __restrict__ dst, int E, int* __restrict__ binCount) {
    __shared__ int h[BINS];
    for (int i = threadIdx.x; i < BINS; i += 256) h[i] = 0;
    __syncthreads();
    for (int e = blockIdx.x * 256 + threadIdx.x; e < E; e += gridDim.x * 256)
        atomicAdd(&h[dst[e] >> 8], 1);
    __syncthreads();
    for (int i = threadIdx.x; i < BINS; i += 256)
        if (h[i]) atomicAdd(&binCount[i], h[i]);
}

// ---------------- phase 2: scan buckets ----------------
__global__ void k_scan_bins(const int* __restrict__ binCount, int* __restrict__ bucketBase,
                            int* __restrict__ binCursor, int* __restrict__ offsets, int E) {
    __shared__ int sd[256];
    int t = threadIdx.x;
    int v = (t < BINS) ? binCount[t] : 0;
    sd[t] = v; __syncthreads();
    for (int off = 1; off < 256; off <<= 1) {
        int tmp = (t >= off) ? sd[t - off] : 0;
        __syncthreads();
        sd[t] += tmp;
        __syncthreads();
    }
    int ex = sd[t] - v;
    if (t < BINS) { bucketBase[t] = ex; binCursor[t] = ex; }
    if (t == 0) { bucketBase[BINS] = E; offsets[N_NODES] = E; }
}

// ---------------- phase 3: partition edges into buckets (1024 thr: 4 iters/pass) ----------------
#define PCHUNK 4096
#define PTHREADS 1024
__launch_bounds__(PTHREADS)
__global__ void k_partition(const int* __restrict__ src, const int* __restrict__ dst, int E,
                            int* __restrict__ binCursor, unsigned int* __restrict__ packed) {
    __shared__ unsigned int lpack[PCHUNK];   // (local_dst<<16)|src
    __shared__ unsigned int lpos[PCHUNK];    // (rank<<8)|bin
    __shared__ int lcnt[BINS];
    __shared__ int lrun[BINS];
    int t = threadIdx.x;
    int base = blockIdx.x * PCHUNK;
    int n = E - base; if (n > PCHUNK) n = PCHUNK;
    for (int i = t; i < BINS; i += PTHREADS) lcnt[i] = 0;
    __syncthreads();
    for (int i = t; i < n; i += PTHREADS) {
        int d = dst[base + i], s = src[base + i];
        int bin = d >> 8;
        unsigned int r = (unsigned int)atomicAdd(&lcnt[bin], 1);
        lpack[i] = ((unsigned int)(d & 255) << 16) | (unsigned int)s;
        lpos[i] = (r << 8) | (unsigned int)bin;
    }
    __syncthreads();
    if (t < BINS && lcnt[t] > 0) lrun[t] = atomicAdd(&binCursor[t], lcnt[t]);
    __syncthreads();
    for (int i = t; i < n; i += PTHREADS) {
        unsigned int p = lpos[i];
        int bin = p & 255;
        unsigned int r = p >> 8;
        packed[(size_t)lrun[bin] + r] = lpack[i];
    }
}

// ---------------- phase 4: per-bucket CSR (1024 thr: 16 waves to hide atomic/scatter latency) ----------------
__launch_bounds__(1024)
__global__ void k_bucket_csr(const unsigned int* __restrict__ packed, const int* __restrict__ bucketBase,
                             int* __restrict__ offsets, float* __restrict__ dinv,
                             unsigned short* __restrict__ col, int N) {
    __shared__ int lcnt[256];
    __shared__ int lscan[256];
    __shared__ int lofs[256];
    int b = blockIdx.x, t = threadIdx.x;
    int s = bucketBase[b], e = bucketBase[b + 1];
    if (t < 256) lcnt[t] = 0;
    __syncthreads();
    for (int i = s + t; i < e; i += 1024) atomicAdd(&lcnt[packed[i] >> 16], 1);
    __syncthreads();
    int v = (t < 256) ? lcnt[t] : 0;
    if (t < 256) lscan[t] = v;
    __syncthreads();
    for (int off = 1; off < 256; off <<= 1) {
        int tmp = (t < 256 && t >= off) ? lscan[t - off] : 0;
        __syncthreads();
        if (t < 256) lscan[t] += tmp;
        __syncthreads();
    }
    if (t < 256) {
        int ex = lscan[t] - v;
        int node = b * 256 + t;
        if (node < N) {
            offsets[node] = s + ex;
            dinv[node] = rsqrtf((float)(v + 1));   // deg incl. self-loop
        }
        lofs[t] = ex;
        lcnt[t] = 0;
    }
    __syncthreads();
    for (int i = s + t; i < e; i += 1024) {
        unsigned int p = packed[i];
        int ld = (int)(p >> 16);
        int r = atomicAdd(&lcnt[ld], 1);
        col[(size_t)s + lofs[ld] + r] = (unsigned short)(p & 0xFFFFu);
    }
}

// ---------------- cast W1 -> bf16 transposed [HID][F_IN] ----------------
__global__ void k_castW1(const float* __restrict__ W1, unsigned short* __restrict__ W1bT) {
    int i = blockIdx.x * 256 + threadIdx.x;   // i = n*256 + k
    if (i < HID * F_IN) {
        int n = i >> 8, k = i & 255;
        W1bT[i] = f2bf(W1[(size_t)k * HID + n]);
    }
}

// ---------------- GEMM1 (MFMA bf16): y1f = fp8((x @ W1) * dinv[row]) ----------------
__launch_bounds__(256)
__global__ void k_gemm1(const float* __restrict__ A, const unsigned short* __restrict__ BT,
                        const float* __restrict__ dinv, unsigned short* __restrict__ Yf, int M) {
    __shared__ __align__(16) unsigned short As[64][72];    // 64 rows x 64 bf16 (+8 pad)
    __shared__ __align__(16) unsigned short Bs[128][72];   // 128 n-rows x 64 bf16 (+8 pad)
    int t = threadIdx.x;
    int w = t >> 6, lane = t & 63;
    int q = lane >> 4, m = lane & 15;
    int row0 = blockIdx.x * 64;

    floatx4 acc[4][2];
#pragma unroll
    for (int rt = 0; rt < 4; rt++)
#pragma unroll
        for (int ct = 0; ct < 2; ct++) acc[rt][ct] = (floatx4){0.f, 0.f, 0.f, 0.f};

    int ar = t >> 2;
    int ac = (t & 3) * 16;
    int brow = t >> 1;
    int bh = (t & 1) * 32;

    for (int k0 = 0; k0 < F_IN; k0 += 64) {
        {
            int grow = row0 + ar;
            float4 v0, v1, v2, v3;
            if (grow < M) {
                const float* sp = A + (size_t)grow * F_IN + k0 + ac;
                v0 = *(const float4*)(sp);     v1 = *(const float4*)(sp + 4);
                v2 = *(const float4*)(sp + 8); v3 = *(const float4*)(sp + 12);
            } else {
                v0 = v1 = v2 = v3 = make_float4(0.f, 0.f, 0.f, 0.f);
            }
            uint4 u0, u1;
            u0.x = pack2bf(v0.x, v0.y); u0.y = pack2bf(v0.z, v0.w);
            u0.z = pack2bf(v1.x, v1.y); u0.w = pack2bf(v1.z, v1.w);
            u1.x = pack2bf(v2.x, v2.y); u1.y = pack2bf(v2.z, v2.w);
            u1.z = pack2bf(v3.x, v3.y); u1.w = pack2bf(v3.z, v3.w);
            *(uint4*)&As[ar][ac] = u0;
            *(uint4*)&As[ar][ac + 8] = u1;
        }
        {
            const unsigned short* sp = BT + (size_t)brow * F_IN + k0 + bh;
            uint4 b0 = *(const uint4*)(sp);
            uint4 b1 = *(const uint4*)(sp + 8);
            uint4 b2 = *(const uint4*)(sp + 16);
            uint4 b3 = *(const uint4*)(sp + 24);
            *(uint4*)&Bs[brow][bh] = b0;
            *(uint4*)&Bs[brow][bh + 8] = b1;
            *(uint4*)&Bs[brow][bh + 16] = b2;
            *(uint4*)&Bs[brow][bh + 24] = b3;
        }
        __syncthreads();
#pragma unroll
        for (int kc = 0; kc < 64; kc += 32) {
            short8 af[4];
#pragma unroll
            for (int rt = 0; rt < 4; rt++)
                af[rt] = *(const short8*)&As[rt * 16 + m][kc + q * 8];
#pragma unroll
            for (int ct = 0; ct < 2; ct++) {
                short8 bfr = *(const short8*)&Bs[w * 32 + ct * 16 + m][kc + q * 8];
#pragma unroll
                for (int rt = 0; rt < 4; rt++)
                    acc[rt][ct] = __builtin_amdgcn_mfma_f32_16x16x32_bf16(af[rt], bfr, acc[rt][ct], 0, 0, 0);
            }
        }
        __syncthreads();
    }
#pragma unroll
    for (int rt = 0; rt < 4; rt++) {
#pragma unroll
        for (int r = 0; r < 4; r++) {
            int grow = row0 + rt * 16 + q * 4 + r;
            if (grow < M) {
                float d = dinv[grow];
                int pk = __builtin_amdgcn_cvt_pk_fp8_f32(acc[rt][0][r] * d, acc[rt][1][r] * d, 0, false);
                Yf[(size_t)grow * 64 + w * 16 + m] = (unsigned short)pk;
            }
        }
    }
}

// ---------------- GEMM2: y2b = bf16((hid @ W2) * dinv[row]) ----------------
__launch_bounds__(256)
__global__ void k_gemm2(const float* __restrict__ A, const float* __restrict__ B,
                        const float* __restrict__ dinv, unsigned short* __restrict__ Yb, int M) {
    const int BM = 128, BK = 32, TM = 4, TN = 5;
    __shared__ float As[BM][BK + 4];
    __shared__ float Bs[BK][C_OUT];
    int t = threadIdx.x;
    int tx = t & 7;
    int ty = t >> 3;
    int row0 = blockIdx.x * BM;
    float acc[TM][TN];
#pragma unroll
    for (int i = 0; i < TM; i++)
#pragma unroll
        for (int j = 0; j < TN; j++) acc[i][j] = 0.f;

    int am = t >> 1;

    for (int k0 = 0; k0 < HID; k0 += BK) {
#pragma unroll
        for (int h = 0; h < 4; h++) {
            int kq = (t & 1) + h * 2;
            int row = row0 + am;
            float4 v = (row < M) ? *(const float4*)(A + (size_t)row * HID + k0 + kq * 4)
                                 : make_float4(0.f, 0.f, 0.f, 0.f);
            As[am][kq * 4 + 0] = v.x; As[am][kq * 4 + 1] = v.y;
            As[am][kq * 4 + 2] = v.z; As[am][kq * 4 + 3] = v.w;
        }
        for (int l = t; l < BK * (C_OUT / 4); l += 256) {
            int kk = l / (C_OUT / 4), qq = l % (C_OUT / 4);
            *(float4*)&Bs[kk][qq * 4] = *(const float4*)(B + (size_t)(k0 + kk) * C_OUT + qq * 4);
        }
        __syncthreads();
#pragma unroll
        for (int kk = 0; kk < BK; kk++) {
            float a[TM], bv[TN];
#pragma unroll
            for (int i = 0; i < TM; i++) a[i] = As[ty * TM + i][kk];
#pragma unroll
            for (int j = 0; j < TN; j++) bv[j] = Bs[kk][tx * TN + j];
#pragma unroll
            for (int i = 0; i < TM; i++)
#pragma unroll
                for (int j = 0; j < TN; j++) acc[i][j] = fmaf(a[i], bv[j], acc[i][j]);
        }
        __syncthreads();
    }
#pragma unroll
    for (int i = 0; i < TM; i++) {
        int row = row0 + ty * TM + i;
        if (row < M) {
            float d = dinv[row];
#pragma unroll
            for (int j = 0; j < TN; j++)
                Yb[(size_t)row * C_OUT + tx * TN + j] = f2bf(acc[i][j] * d);
        }
    }
}

// ---------------- agg1: 16 lanes/edge (uint2 fp8 = 8 features), 4 edge groups ----------------
// y1f row = 64 ushorts (128 B). Lane lg covers ushorts lg*4..lg*4+3.
// ushort p -> features f_lo = (p>>4)*32 + (p&15), f_hi = f_lo + 16.
// Edge ids staged via LDS 4x16 transpose (edge q -> slot (q&3)*16+(q>>2)); group g
// reads its 16 edge ids contiguously. Gathers batched 4-deep.
__device__ __forceinline__ void fp8acc8(uint2 v, floatx2* a) {
    a[0] += __builtin_amdgcn_cvt_pk_f32_fp8(v.x, false);
    a[1] += __builtin_amdgcn_cvt_pk_f32_fp8(v.x, true);
    a[2] += __builtin_amdgcn_cvt_pk_f32_fp8(v.y, false);
    a[3] += __builtin_amdgcn_cvt_pk_f32_fp8(v.y, true);
}

__launch_bounds__(256)
__global__ void k_agg1(const uint2* __restrict__ y1p, const unsigned short* __restrict__ col,
                       const int* __restrict__ offsets, const float* __restrict__ dinv,
                       const float* __restrict__ b1, float* __restrict__ hid, int N) {
    __shared__ __align__(16) unsigned short jT[4][64];   // per-wave transposed col window
    int lane = threadIdx.x & 63;
    int w = threadIdx.x >> 6;
    int node = blockIdx.x * 4 + w;
    if (node >= N) return;
    int g = lane >> 4;      // edge group 0..3
    int lg = lane & 15;     // 16 lanes x uint2 = 128 B row
    int s = offsets[node], e = offsets[node + 1];

    floatx2 acc2[4];
#pragma unroll
    for (int i = 0; i < 4; i++) acc2[i] = (floatx2){0.f, 0.f};
    if (g == 0) fp8acc8(y1p[(size_t)node * 16 + lg], acc2);   // self-loop

    for (int t0 = s; t0 < e; t0 += 64) {
        int cnt = e - t0; if (cnt > 64) cnt = 64;
        // stage col window, transposed: edge q -> LDS slot (q&3)*16 + (q>>2),
        // so group g reads its 16 edge ids (q = p*4+g, p=0..15) contiguously.
        unsigned short jv = (lane < cnt) ? col[t0 + lane] : (unsigned short)0;
        jT[w][(lane & 3) * 16 + (lane >> 2)] = jv;
        uint4 c0 = *(const uint4*)&jT[w][g * 16];        // p = 0..7
        uint4 c1 = *(const uint4*)&jT[w][g * 16 + 8];    // p = 8..15
        unsigned int cw[8] = {c0.x, c0.y, c0.z, c0.w, c1.x, c1.y, c1.z, c1.w};
        int cg = cnt - g;   // pass p valid iff p*4 < cg

#pragma unroll
        for (int pb = 0; pb < 4; ++pb) {
            if (pb * 16 >= cnt) break;               // uniform: no group has edges left
            if (pb * 16 + 16 <= cnt) {               // uniform: all 4 passes full
                uint2 u[4];
#pragma unroll
                for (int qq = 0; qq < 4; ++qq) {
                    int p = pb * 4 + qq;
                    unsigned int word = cw[p >> 1];
                    int j = (p & 1) ? (int)(word >> 16) : (int)(word & 0xFFFFu);
                    u[qq] = y1p[(size_t)j * 16 + lg];
                }
#pragma unroll
                for (int qq = 0; qq < 4; ++qq) fp8acc8(u[qq], acc2);
            } else {                                  // boundary block: batched issue/consume
                uint2 u[4];
#pragma unroll
                for (int qq = 0; qq < 4; ++qq) {
                    int p = pb * 4 + qq;
                    if (p * 4 >= cnt) break;         // uniform
                    unsigned int word = cw[p >> 1];
                    int j = (p & 1) ? (int)(word >> 16) : (int)(word & 0xFFFFu);
                    u[qq] = y1p[(size_t)j * 16 + lg];
                }
#pragma unroll
                for (int qq = 0; qq < 4; ++qq) {
                    int p = pb * 4 + qq;
                    if (p * 4 >= cnt) break;         // uniform
                    uint2 v = u[qq];
                    if (p * 4 >= cg) { v.x = 0u; v.y = 0u; }   // invalid lane-group: add 0
                    fp8acc8(v, acc2);
                }
            }
        }
    }
    // reduce across 4 edge groups (lanes at stride 16)
#pragma unroll
    for (int k = 0; k < 4; k++) {
        acc2[k][0] += __shfl(acc2[k][0], lane + 32);
        acc2[k][1] += __shfl(acc2[k][1], lane + 32);
    }
#pragma unroll
    for (int k = 0; k < 4; k++) {
        acc2[k][0] += __shfl(acc2[k][0], lane + 16);
        acc2[k][1] += __shfl(acc2[k][1], lane + 16);
    }
    if (g == 0) {
        float d = dinv[node];
        int base = (lg >> 2) * 32 + (lg & 3) * 4;
        float4 bL = *(const float4*)(b1 + base);
        float4 bH = *(const float4*)(b1 + base + 16);
        float4 oL, oH;
        oL.x = fmaxf(fmaf(d, acc2[0][0], bL.x), 0.f);
        oL.y = fmaxf(fmaf(d, acc2[1][0], bL.y), 0.f);
        oL.z = fmaxf(fmaf(d, acc2[2][0], bL.z), 0.f);
        oL.w = fmaxf(fmaf(d, acc2[3][0], bL.w), 0.f);
        oH.x = fmaxf(fmaf(d, acc2[0][1], bH.x), 0.f);
        oH.y = fmaxf(fmaf(d, acc2[1][1], bH.y), 0.f);
        oH.z = fmaxf(fmaf(d, acc2[2][1], bH.z), 0.f);
        oH.w = fmaxf(fmaf(d, acc2[3][1], bH.w), 0.f);
        float* op = hid + (size_t)node * HID + base;
        *(float4*)(op) = oL;
        *(float4*)(op + 16) = oH;
    }
}

// ---------------- agg2: 10 lanes/edge (uint2), 6 edges/pass + softmax ----------------
// Round-2 shuffle indexing and accumulation set/order; gathers issued up to
// 10-deep via NAMED scalar uint2s with unconditional defs inside wave-uniform
// guards (np > P) so SROA keeps them in VGPRs (rule: conditional-def arrays get
// demoted to LDS scratch by promote-alloca — round 6: 20 KB/block, 1.6M conflicts).
__launch_bounds__(256)
__global__ void k_agg2(const uint2* __restrict__ y2b2, const unsigned short* __restrict__ col,
                       const int* __restrict__ offsets, const float* __restrict__ dinv,
                       const float* __restrict__ b2, float* __restrict__ x2out,
                       float* __restrict__ logp, int N) {
    int lane = threadIdx.x & 63;
    int w = threadIdx.x >> 6;
    int node = blockIdx.x * 4 + w;
    if (node >= N) return;
    int g = lane / 10;
    int lg = lane - g * 10;
    bool lact = lane < 60;
    int s = offsets[node], e = offsets[node + 1];

    float a0, a1, a2, a3;
    if (lact && g == 0) {
        uint2 sv = y2b2[(size_t)node * 10 + lg];
        a0 = bf_lo(sv.x); a1 = bf_hi(sv.x); a2 = bf_lo(sv.y); a3 = bf_hi(sv.y);
    } else { a0 = a1 = a2 = a3 = 0.f; }

    for (int t0 = s; t0 < e; t0 += 60) {
        int cnt = e - t0; if (cnt > 60) cnt = 60;
        int jreg = (lane < cnt) ? (int)col[t0 + lane] : 0;
        int np = (cnt + 5) / 6;          // uniform pass count, 1..10
        int cg = lact ? (cnt - g) : 0;   // pass P accumulates iff P*6 < cg
        uint2 u0, u1, u2, u3, u4, u5, u6, u7, u8, u9;
#define AG2_ISSUE(P, U) if (np > P) { int j = __shfl(jreg, P * 6 + g); U = y2b2[(size_t)j * 10 + lg]; }
        AG2_ISSUE(0, u0) AG2_ISSUE(1, u1) AG2_ISSUE(2, u2) AG2_ISSUE(3, u3) AG2_ISSUE(4, u4)
        AG2_ISSUE(5, u5) AG2_ISSUE(6, u6) AG2_ISSUE(7, u7) AG2_ISSUE(8, u8) AG2_ISSUE(9, u9)
#undef AG2_ISSUE
#define AG2_CONS(P, U) if (np > P) { if (P * 6 < cg) { \
            a0 += bf_lo(U.x); a1 += bf_hi(U.x); a2 += bf_lo(U.y); a3 += bf_hi(U.y); } }
        AG2_CONS(0, u0) AG2_CONS(1, u1) AG2_CONS(2, u2) AG2_CONS(3, u3) AG2_CONS(4, u4)
        AG2_CONS(5, u5) AG2_CONS(6, u6) AG2_CONS(7, u7) AG2_CONS(8, u8) AG2_CONS(9, u9)
#undef AG2_CONS
    }
    a0 += __shfl(a0, lane + 30); a1 += __shfl(a1, lane + 30);
    a2 += __shfl(a2, lane + 30); a3 += __shfl(a3, lane + 30);
    float r0 = a0 + __shfl(a0, lane + 10) + __shfl(a0, lane + 20);
    float r1 = a1 + __shfl(a1, lane + 10) + __shfl(a1, lane + 20);
    float r2 = a2 + __shfl(a2, lane + 10) + __shfl(a2, lane + 20);
    float r3 = a3 + __shfl(a3, lane + 10) + __shfl(a3, lane + 20);

    float x0, x1, x2v, x3;
    if (lane < 10) {
        float d = dinv[node];
        float4 bb = ((const float4*)b2)[lg];
        x0 = fmaf(d, r0, bb.x); x1 = fmaf(d, r1, bb.y);
        x2v = fmaf(d, r2, bb.z); x3 = fmaf(d, r3, bb.w);
        float4* xo = (float4*)(x2out + (size_t)node * C_OUT);
        xo[lg] = make_float4(x0, x1, x2v, x3);
    } else { x0 = x1 = x2v = x3 = -INFINITY; }

    float m = fmaxf(fmaxf(x0, x1), fmaxf(x2v, x3));
#pragma unroll
    for (int off = 1; off < 16; off <<= 1) m = fmaxf(m, __shfl_xor(m, off));
    float sum = (lane < 10) ? (expf(x0 - m) + expf(x1 - m) + expf(x2v - m) + expf(x3 - m)) : 0.f;
#pragma unroll
    for (int off = 1; off < 16; off <<= 1) sum += __shfl_xor(sum, off);
    if (lane < 10) {
        float lse = m + logf(sum);
        float4* lo = (float4*)(logp + (size_t)node * C_OUT);
        lo[lg] = make_float4(x0 - lse, x1 - lse, x2v - lse, x3 - lse);
    }
}

// ---------------- launcher ----------------
extern "C" void kernel_launch(void* const* d_in, const int* in_sizes, int n_in,
                              void* d_out, int out_size, void* d_ws, size_t ws_size,
                              hipStream_t stream) {
    const float* x  = (const float*)d_in[0];
    const int*   ei = (const int*)d_in[1];
    const float* W1 = (const float*)d_in[2];
    const float* b1 = (const float*)d_in[3];
    const float* W2 = (const float*)d_in[4];
    const float* b2 = (const float*)d_in[5];
    const int N = N_NODES;
    const int E = in_sizes[1] / 2;
    const int* src = ei;
    const int* dst = ei + E;

    float* out_hid  = (float*)d_out;                       // N*128
    float* out_x2   = out_hid + (size_t)N * HID;           // N*40
    float* out_logp = out_x2 + (size_t)N * C_OUT;          // N*40

    char* p = (char*)d_ws;
    auto alloc = [&](size_t bytes) { void* r = (void*)p; p += (bytes + 255) & ~255ull; return r; };
    int*   binCount   = (int*)alloc((size_t)BINS * 4);
    int*   bucketBase = (int*)alloc((size_t)(BINS + 1) * 4);
    int*   binCursor  = (int*)alloc((size_t)BINS * 4);
    int*   offsets    = (int*)alloc((size_t)(N + 1) * 4);
    float* dinv       = (float*)alloc((size_t)N * 4);
    unsigned int*   packed = (unsigned int*)alloc((size_t)E * 4);
    unsigned short* col    = (unsigned short*)alloc((size_t)(E + 64) * 2);
    unsigned short* y1f    = (unsigned short*)alloc((size_t)N * 64 * 2);        // fp8 pairs
    unsigned short* y2b    = (unsigned short*)alloc((size_t)N * C_OUT * 2);     // bf16
    unsigned short* W1bT   = (unsigned short*)alloc((size_t)HID * F_IN * 2);    // bf16 [N][K]

    hipMemsetAsync(binCount, 0, (size_t)BINS * 4, stream);
    k_hist<<<512, 256, 0, stream>>>(dst, E, binCount);
    k_scan_bins<<<1, 256, 0, stream>>>(binCount, bucketBase, binCursor, offsets, E);
    k_partition<<<(E + PCHUNK - 1) / PCHUNK, PTHREADS, 0, stream>>>(src, dst, E, binCursor, packed);
    k_bucket_csr<<<BINS, 1024, 0, stream>>>(packed, bucketBase, offsets, dinv, col, N);
    k_castW1<<<(HID * F_IN + 255) / 256, 256, 0, stream>>>(W1, W1bT);
    k_gemm1<<<(N + 63) / 64, 256, 0, stream>>>(x, W1bT, dinv, y1f, N);
    k_agg1<<<(N + 3) / 4, 256, 0, stream>>>((const uint2*)y1f, col, offsets, dinv, b1, out_hid, N);
    k_gemm2<<<(N + 127) / 128, 256, 0, stream>>>(out_hid, W2, dinv, y2b, N);
    k_agg2<<<(N + 3) / 4, 256, 0, stream>>>((const uint2*)y2b, col, offsets, dinv, b2, out_x2, out_logp, N);
}

// Round 9
// 236.050 us; speedup vs baseline: 1.1874x; 1.0138x over previous
//
#include <hip/hip_runtime.h>
#include <math.h>

#define N_NODES 50000
#define F_IN 256
#define HID 128
#define C_OUT 40
#define BINS ((N_NODES + 255) / 256)   // 196 buckets of 256 nodes

typedef __attribute__((ext_vector_type(8))) short short8;
typedef __attribute__((ext_vector_type(4))) float floatx4;
typedef __attribute__((ext_vector_type(2))) float floatx2;

__device__ __forceinline__ unsigned short f2bf(float f) {
    unsigned int u = __float_as_uint(f);
    unsigned int r = (u + 0x7FFFu + ((u >> 16) & 1u)) >> 16;
    return (unsigned short)r;
}
// HW bf16 pair conversion (RNE, same as f2bf for finite values): clang fuses
// adjacent __bf16 casts into one v_cvt_pk_bf16_f32 — ~12x fewer VALU inst than
// the manual bit-twiddle (gemm1 does 12.8M conversions = ~33 us at 5-6 inst each).
__device__ __forceinline__ unsigned int pack2bf(float a, float b) {
    __bf16 ha = (__bf16)a, hb = (__bf16)b;
    unsigned short ua, ub;
    __builtin_memcpy(&ua, &ha, 2);
    __builtin_memcpy(&ub, &hb, 2);
    return (unsigned int)ua | ((unsigned int)ub << 16);
}
__device__ __forceinline__ float bf_lo(unsigned int u) { return __uint_as_float(u << 16); }
__device__ __forceinline__ float bf_hi(unsigned int u) { return __uint_as_float(u & 0xFFFF0000u); }

// ---------------- phase 1: bucket histogram ----------------
__global__ void k_hist(const int* __restrict__ dst, int E, int* __restrict__ binCount) {
    __shared__ int h[BINS];
    for (int i = threadIdx.x; i < BINS; i += 256) h[i] = 0;
    __syncthreads();
    for (int e = blockIdx.x * 256 + threadIdx.x; e < E; e += gridDim.x * 256)
        atomicAdd(&h[dst[e] >> 8], 1);
    __syncthreads();
    for (int i = threadIdx.x; i < BINS; i += 256)
        if (h[i]) atomicAdd(&binCount[i], h[i]);
}

// ---------------- phase 2: scan buckets ----------------
__global__ void k_scan_bins(const int* __restrict__ binCount, int* __restrict__ bucketBase,
                            int* __restrict__ binCursor, int* __restrict__ offsets, int E) {
    __shared__ int sd[256];
    int t = threadIdx.x;
    int v = (t < BINS) ? binCount[t] : 0;
    sd[t] = v; __syncthreads();
    for (int off = 1; off < 256; off <<= 1) {
        int tmp = (t >= off) ? sd[t - off] : 0;
        __syncthreads();
        sd[t] += tmp;
        __syncthreads();
    }
    int ex = sd[t] - v;
    if (t < BINS) { bucketBase[t] = ex; binCursor[t] = ex; }
    if (t == 0) { bucketBase[BINS] = E; offsets[N_NODES] = E; }
}

// ---------------- phase 3: partition edges into buckets (1024 thr: 4 iters/pass) ----------------
#define PCHUNK 4096
#define PTHREADS 1024
__launch_bounds__(PTHREADS)
__global__ void k_partition(const int* __restrict__ src, const int* __restrict__ dst, int E,
                            int* __restrict__ binCursor, unsigned int* __restrict__ packed) {
    __shared__ unsigned int lpack[PCHUNK];   // (local_dst<<16)|src
    __shared__ unsigned int lpos[PCHUNK];    // (rank<<8)|bin
    __shared__ int lcnt[BINS];
    __shared__ int lrun[BINS];
    int t = threadIdx.x;
    int base = blockIdx.x * PCHUNK;
    int n = E - base; if (n > PCHUNK) n = PCHUNK;
    for (int i = t; i < BINS; i += PTHREADS) lcnt[i] = 0;
    __syncthreads();
    for (int i = t; i < n; i += PTHREADS) {
        int d = dst[base + i], s = src[base + i];
        int bin = d >> 8;
        unsigned int r = (unsigned int)atomicAdd(&lcnt[bin], 1);
        lpack[i] = ((unsigned int)(d & 255) << 16) | (unsigned int)s;
        lpos[i] = (r << 8) | (unsigned int)bin;
    }
    __syncthreads();
    if (t < BINS && lcnt[t] > 0) lrun[t] = atomicAdd(&binCursor[t], lcnt[t]);
    __syncthreads();
    for (int i = t; i < n; i += PTHREADS) {
        unsigned int p = lpos[i];
        int bin = p & 255;
        unsigned int r = p >> 8;
        packed[(size_t)lrun[bin] + r] = lpack[i];
    }
}

// ---------------- phase 4: per-bucket CSR (1024 thr: 16 waves to hide atomic/scatter latency) ----------------
__launch_bounds__(1024)
__global__ void k_bucket_csr(const unsigned int* __restrict__ packed, const int* __restrict__ bucketBase,
                             int* __restrict__ offsets, float* __restrict__ dinv,
                             unsigned short* __restrict__ col, int N) {
    __shared__ int lcnt[256];
    __shared__ int lscan[256];
    __shared__ int lofs[256];
    int b = blockIdx.x, t = threadIdx.x;
    int s = bucketBase[b], e = bucketBase[b + 1];
    if (t < 256) lcnt[t] = 0;
    __syncthreads();
    for (int i = s + t; i < e; i += 1024) atomicAdd(&lcnt[packed[i] >> 16], 1);
    __syncthreads();
    int v = (t < 256) ? lcnt[t] : 0;
    if (t < 256) lscan[t] = v;
    __syncthreads();
    for (int off = 1; off < 256; off <<= 1) {
        int tmp = (t < 256 && t >= off) ? lscan[t - off] : 0;
        __syncthreads();
        if (t < 256) lscan[t] += tmp;
        __syncthreads();
    }
    if (t < 256) {
        int ex = lscan[t] - v;
        int node = b * 256 + t;
        if (node < N) {
            offsets[node] = s + ex;
            dinv[node] = rsqrtf((float)(v + 1));   // deg incl. self-loop
        }
        lofs[t] = ex;
        lcnt[t] = 0;
    }
    __syncthreads();
    for (int i = s + t; i < e; i += 1024) {
        unsigned int p = packed[i];
        int ld = (int)(p >> 16);
        int r = atomicAdd(&lcnt[ld], 1);
        col[(size_t)s + lofs[ld] + r] = (unsigned short)(p & 0xFFFFu);
    }
}

// ---------------- cast W1 -> bf16 transposed [HID][F_IN] ----------------
__global__ void k_castW1(const float* __restrict__ W1, unsigned short* __restrict__ W1bT) {
    int i = blockIdx.x * 256 + threadIdx.x;   // i = n*256 + k
    if (i < HID * F_IN) {
        int n = i >> 8, k = i & 255;
        W1bT[i] = f2bf(W1[(size_t)k * HID + n]);
    }
}

// ---------------- GEMM1 (MFMA bf16): y1f = fp8((x @ W1) * dinv[row]) ----------------
__launch_bounds__(256)
__global__ void k_gemm1(const float* __restrict__ A, const unsigned short* __restrict__ BT,
                        const float* __restrict__ dinv, unsigned short* __restrict__ Yf, int M) {
    __shared__ __align__(16) unsigned short As[64][72];    // 64 rows x 64 bf16 (+8 pad)
    __shared__ __align__(16) unsigned short Bs[128][72];   // 128 n-rows x 64 bf16 (+8 pad)
    int t = threadIdx.x;
    int w = t >> 6, lane = t & 63;
    int q = lane >> 4, m = lane & 15;
    int row0 = blockIdx.x * 64;

    floatx4 acc[4][2];
#pragma unroll
    for (int rt = 0; rt < 4; rt++)
#pragma unroll
        for (int ct = 0; ct < 2; ct++) acc[rt][ct] = (floatx4){0.f, 0.f, 0.f, 0.f};

    int ar = t >> 2;
    int ac = (t & 3) * 16;
    int brow = t >> 1;
    int bh = (t & 1) * 32;

    for (int k0 = 0; k0 < F_IN; k0 += 64) {
        {
            int grow = row0 + ar;
            float4 v0, v1, v2, v3;
            if (grow < M) {
                const float* sp = A + (size_t)grow * F_IN + k0 + ac;
                v0 = *(const float4*)(sp);     v1 = *(const float4*)(sp + 4);
                v2 = *(const float4*)(sp + 8); v3 = *(const float4*)(sp + 12);
            } else {
                v0 = v1 = v2 = v3 = make_float4(0.f, 0.f, 0.f, 0.f);
            }
            uint4 u0, u1;
            u0.x = pack2bf(v0.x, v0.y); u0.y = pack2bf(v0.z, v0.w);
            u0.z = pack2bf(v1.x, v1.y); u0.w = pack2bf(v1.z, v1.w);
            u1.x = pack2bf(v2.x, v2.y); u1.y = pack2bf(v2.z, v2.w);
            u1.z = pack2bf(v3.x, v3.y); u1.w = pack2bf(v3.z, v3.w);
            *(uint4*)&As[ar][ac] = u0;
            *(uint4*)&As[ar][ac + 8] = u1;
        }
        {
            const unsigned short* sp = BT + (size_t)brow * F_IN + k0 + bh;
            uint4 b0 = *(const uint4*)(sp);
            uint4 b1 = *(const uint4*)(sp + 8);
            uint4 b2 = *(const uint4*)(sp + 16);
            uint4 b3 = *(const uint4*)(sp + 24);
            *(uint4*)&Bs[brow][bh] = b0;
            *(uint4*)&Bs[brow][bh + 8] = b1;
            *(uint4*)&Bs[brow][bh + 16] = b2;
            *(uint4*)&Bs[brow][bh + 24] = b3;
        }
        __syncthreads();
#pragma unroll
        for (int kc = 0; kc < 64; kc += 32) {
            short8 af[4];
#pragma unroll
            for (int rt = 0; rt < 4; rt++)
                af[rt] = *(const short8*)&As[rt * 16 + m][kc + q * 8];
#pragma unroll
            for (int ct = 0; ct < 2; ct++) {
                short8 bfr = *(const short8*)&Bs[w * 32 + ct * 16 + m][kc + q * 8];
#pragma unroll
                for (int rt = 0; rt < 4; rt++)
                    acc[rt][ct] = __builtin_amdgcn_mfma_f32_16x16x32_bf16(af[rt], bfr, acc[rt][ct], 0, 0, 0);
            }
        }
        __syncthreads();
    }
#pragma unroll
    for (int rt = 0; rt < 4; rt++) {
#pragma unroll
        for (int r = 0; r < 4; r++) {
            int grow = row0 + rt * 16 + q * 4 + r;
            if (grow < M) {
                float d = dinv[grow];
                int pk = __builtin_amdgcn_cvt_pk_fp8_f32(acc[rt][0][r] * d, acc[rt][1][r] * d, 0, false);
                Yf[(size_t)grow * 64 + w * 16 + m] = (unsigned short)pk;
            }
        }
    }
}

// ---------------- GEMM2: y2b = bf16((hid @ W2) * dinv[row]) ----------------
__launch_bounds__(256)
__global__ void k_gemm2(const float* __restrict__ A, const float* __restrict__ B,
                        const float* __restrict__ dinv, unsigned short* __restrict__ Yb, int M) {
    const int BM = 128, BK = 32, TM = 4, TN = 5;
    __shared__ float As[BM][BK + 4];
    __shared__ float Bs[BK][C_OUT];
    int t = threadIdx.x;
    int tx = t & 7;
    int ty = t >> 3;
    int row0 = blockIdx.x * BM;
    float acc[TM][TN];
#pragma unroll
    for (int i = 0; i < TM; i++)
#pragma unroll
        for (int j = 0; j < TN; j++) acc[i][j] = 0.f;

    int am = t >> 1;

    for (int k0 = 0; k0 < HID; k0 += BK) {
#pragma unroll
        for (int h = 0; h < 4; h++) {
            int kq = (t & 1) + h * 2;
            int row = row0 + am;
            float4 v = (row < M) ? *(const float4*)(A + (size_t)row * HID + k0 + kq * 4)
                                 : make_float4(0.f, 0.f, 0.f, 0.f);
            As[am][kq * 4 + 0] = v.x; As[am][kq * 4 + 1] = v.y;
            As[am][kq * 4 + 2] = v.z; As[am][kq * 4 + 3] = v.w;
        }
        for (int l = t; l < BK * (C_OUT / 4); l += 256) {
            int kk = l / (C_OUT / 4), qq = l % (C_OUT / 4);
            *(float4*)&Bs[kk][qq * 4] = *(const float4*)(B + (size_t)(k0 + kk) * C_OUT + qq * 4);
        }
        __syncthreads();
#pragma unroll
        for (int kk = 0; kk < BK; kk++) {
            float a[TM], bv[TN];
#pragma unroll
            for (int i = 0; i < TM; i++) a[i] = As[ty * TM + i][kk];
#pragma unroll
            for (int j = 0; j < TN; j++) bv[j] = Bs[kk][tx * TN + j];
#pragma unroll
            for (int i = 0; i < TM; i++)
#pragma unroll
                for (int j = 0; j < TN; j++) acc[i][j] = fmaf(a[i], bv[j], acc[i][j]);
        }
        __syncthreads();
    }
#pragma unroll
    for (int i = 0; i < TM; i++) {
        int row = row0 + ty * TM + i;
        if (row < M) {
            float d = dinv[row];
#pragma unroll
            for (int j = 0; j < TN; j++)
                Yb[(size_t)row * C_OUT + tx * TN + j] = f2bf(acc[i][j] * d);
        }
    }
}

// ---------------- agg1: 16 lanes/edge (uint2 fp8 = 8 features), 4 edge groups ----------------
// y1f row = 64 ushorts (128 B). Lane lg covers ushorts lg*4..lg*4+3.
// ushort p -> features f_lo = (p>>4)*32 + (p&15), f_hi = f_lo + 16.
// Edge ids staged via LDS 4x16 transpose (edge q -> slot (q&3)*16+(q>>2)); group g
// reads its 16 edge ids contiguously. Gathers batched 4-deep.
__device__ __forceinline__ void fp8acc8(uint2 v, floatx2* a) {
    a[0] += __builtin_amdgcn_cvt_pk_f32_fp8(v.x, false);
    a[1] += __builtin_amdgcn_cvt_pk_f32_fp8(v.x, true);
    a[2] += __builtin_amdgcn_cvt_pk_f32_fp8(v.y, false);
    a[3] += __builtin_amdgcn_cvt_pk_f32_fp8(v.y, true);
}

__launch_bounds__(256)
__global__ void k_agg1(const uint2* __restrict__ y1p, const unsigned short* __restrict__ col,
                       const int* __restrict__ offsets, const float* __restrict__ dinv,
                       const float* __restrict__ b1, float* __restrict__ hid, int N) {
    __shared__ __align__(16) unsigned short jT[4][64];   // per-wave transposed col window
    int lane = threadIdx.x & 63;
    int w = threadIdx.x >> 6;
    int node = blockIdx.x * 4 + w;
    if (node >= N) return;
    int g = lane >> 4;      // edge group 0..3
    int lg = lane & 15;     // 16 lanes x uint2 = 128 B row
    int s = offsets[node], e = offsets[node + 1];

    floatx2 acc2[4];
#pragma unroll
    for (int i = 0; i < 4; i++) acc2[i] = (floatx2){0.f, 0.f};
    if (g == 0) fp8acc8(y1p[(size_t)node * 16 + lg], acc2);   // self-loop

    for (int t0 = s; t0 < e; t0 += 64) {
        int cnt = e - t0; if (cnt > 64) cnt = 64;
        // stage col window, transposed: edge q -> LDS slot (q&3)*16 + (q>>2),
        // so group g reads its 16 edge ids (q = p*4+g, p=0..15) contiguously.
        unsigned short jv = (lane < cnt) ? col[t0 + lane] : (unsigned short)0;
        jT[w][(lane & 3) * 16 + (lane >> 2)] = jv;
        uint4 c0 = *(const uint4*)&jT[w][g * 16];        // p = 0..7
        uint4 c1 = *(const uint4*)&jT[w][g * 16 + 8];    // p = 8..15
        unsigned int cw[8] = {c0.x, c0.y, c0.z, c0.w, c1.x, c1.y, c1.z, c1.w};
        int cg = cnt - g;   // pass p valid iff p*4 < cg

#pragma unroll
        for (int pb = 0; pb < 4; ++pb) {
            if (pb * 16 >= cnt) break;               // uniform: no group has edges left
            if (pb * 16 + 16 <= cnt) {               // uniform: all 4 passes full
                uint2 u[4];
#pragma unroll
                for (int qq = 0; qq < 4; ++qq) {
                    int p = pb * 4 + qq;
                    unsigned int word = cw[p >> 1];
                    int j = (p & 1) ? (int)(word >> 16) : (int)(word & 0xFFFFu);
                    u[qq] = y1p[(size_t)j * 16 + lg];
                }
#pragma unroll
                for (int qq = 0; qq < 4; ++qq) fp8acc8(u[qq], acc2);
            } else {                                  // boundary block: batched issue/consume
                uint2 u[4];
#pragma unroll
                for (int qq = 0; qq < 4; ++qq) {
                    int p = pb * 4 + qq;
                    if (p * 4 >= cnt) break;         // uniform
                    unsigned int word = cw[p >> 1];
                    int j = (p & 1) ? (int)(word >> 16) : (int)(word & 0xFFFFu);
                    u[qq] = y1p[(size_t)j * 16 + lg];
                }
#pragma unroll
                for (int qq = 0; qq < 4; ++qq) {
                    int p = pb * 4 + qq;
                    if (p * 4 >= cnt) break;         // uniform
                    uint2 v = u[qq];
                    if (p * 4 >= cg) { v.x = 0u; v.y = 0u; }   // invalid lane-group: add 0
                    fp8acc8(v, acc2);
                }
            }
        }
    }
    // reduce across 4 edge groups (lanes at stride 16)
#pragma unroll
    for (int k = 0; k < 4; k++) {
        acc2[k][0] += __shfl(acc2[k][0], lane + 32);
        acc2[k][1] += __shfl(acc2[k][1], lane + 32);
    }
#pragma unroll
    for (int k = 0; k < 4; k++) {
        acc2[k][0] += __shfl(acc2[k][0], lane + 16);
        acc2[k][1] += __shfl(acc2[k][1], lane + 16);
    }
    if (g == 0) {
        float d = dinv[node];
        int base = (lg >> 2) * 32 + (lg & 3) * 4;
        float4 bL = *(const float4*)(b1 + base);
        float4 bH = *(const float4*)(b1 + base + 16);
        float4 oL, oH;
        oL.x = fmaxf(fmaf(d, acc2[0][0], bL.x), 0.f);
        oL.y = fmaxf(fmaf(d, acc2[1][0], bL.y), 0.f);
        oL.z = fmaxf(fmaf(d, acc2[2][0], bL.z), 0.f);
        oL.w = fmaxf(fmaf(d, acc2[3][0], bL.w), 0.f);
        oH.x = fmaxf(fmaf(d, acc2[0][1], bH.x), 0.f);
        oH.y = fmaxf(fmaf(d, acc2[1][1], bH.y), 0.f);
        oH.z = fmaxf(fmaf(d, acc2[2][1], bH.z), 0.f);
        oH.w = fmaxf(fmaf(d, acc2[3][1], bH.w), 0.f);
        float* op = hid + (size_t)node * HID + base;
        *(float4*)(op) = oL;
        *(float4*)(op + 16) = oH;
    }
}

// ---------------- agg2: 10 lanes/edge (uint2), 6 edges/pass + softmax ----------------
// Round-2 shuffle indexing and accumulation set/order; gathers issued up to
// 10-deep via NAMED scalar uint2s with unconditional defs inside wave-uniform
// guards (np > P) so SROA keeps them in VGPRs (rule: conditional-def arrays get
// demoted to LDS scratch by promote-alloca — round 6: 20 KB/block, 1.6M conflicts).
__launch_bounds__(256)
__global__ void k_agg2(const uint2* __restrict__ y2b2, const unsigned short* __restrict__ col,
                       const int* __restrict__ offsets, const float* __restrict__ dinv,
                       const float* __restrict__ b2, float* __restrict__ x2out,
                       float* __restrict__ logp, int N) {
    int lane = threadIdx.x & 63;
    int w = threadIdx.x >> 6;
    int node = blockIdx.x * 4 + w;
    if (node >= N) return;
    int g = lane / 10;
    int lg = lane - g * 10;
    bool lact = lane < 60;
    int s = offsets[node], e = offsets[node + 1];

    float a0, a1, a2, a3;
    if (lact && g == 0) {
        uint2 sv = y2b2[(size_t)node * 10 + lg];
        a0 = bf_lo(sv.x); a1 = bf_hi(sv.x); a2 = bf_lo(sv.y); a3 = bf_hi(sv.y);
    } else { a0 = a1 = a2 = a3 = 0.f; }

    for (int t0 = s; t0 < e; t0 += 60) {
        int cnt = e - t0; if (cnt > 60) cnt = 60;
        int jreg = (lane < cnt) ? (int)col[t0 + lane] : 0;
        int np = (cnt + 5) / 6;          // uniform pass count, 1..10
        int cg = lact ? (cnt - g) : 0;   // pass P accumulates iff P*6 < cg
        uint2 u0, u1, u2, u3, u4, u5, u6, u7, u8, u9;
#define AG2_ISSUE(P, U) if (np > P) { int j = __shfl(jreg, P * 6 + g); U = y2b2[(size_t)j * 10 + lg]; }
        AG2_ISSUE(0, u0) AG2_ISSUE(1, u1) AG2_ISSUE(2, u2) AG2_ISSUE(3, u3) AG2_ISSUE(4, u4)
        AG2_ISSUE(5, u5) AG2_ISSUE(6, u6) AG2_ISSUE(7, u7) AG2_ISSUE(8, u8) AG2_ISSUE(9, u9)
#undef AG2_ISSUE
#define AG2_CONS(P, U) if (np > P) { if (P * 6 < cg) { \
            a0 += bf_lo(U.x); a1 += bf_hi(U.x); a2 += bf_lo(U.y); a3 += bf_hi(U.y); } }
        AG2_CONS(0, u0) AG2_CONS(1, u1) AG2_CONS(2, u2) AG2_CONS(3, u3) AG2_CONS(4, u4)
        AG2_CONS(5, u5) AG2_CONS(6, u6) AG2_CONS(7, u7) AG2_CONS(8, u8) AG2_CONS(9, u9)
#undef AG2_CONS
    }
    a0 += __shfl(a0, lane + 30); a1 += __shfl(a1, lane + 30);
    a2 += __shfl(a2, lane + 30); a3 += __shfl(a3, lane + 30);
    float r0 = a0 + __shfl(a0, lane + 10) + __shfl(a0, lane + 20);
    float r1 = a1 + __shfl(a1, lane + 10) + __shfl(a1, lane + 20);
    float r2 = a2 + __shfl(a2, lane + 10) + __shfl(a2, lane + 20);
    float r3 = a3 + __shfl(a3, lane + 10) + __shfl(a3, lane + 20);

    float x0, x1, x2v, x3;
    if (lane < 10) {
        float d = dinv[node];
        float4 bb = ((const float4*)b2)[lg];
        x0 = fmaf(d, r0, bb.x); x1 = fmaf(d, r1, bb.y);
        x2v = fmaf(d, r2, bb.z); x3 = fmaf(d, r3, bb.w);
        float4* xo = (float4*)(x2out + (size_t)node * C_OUT);
        xo[lg] = make_float4(x0, x1, x2v, x3);
    } else { x0 = x1 = x2v = x3 = -INFINITY; }

    float m = fmaxf(fmaxf(x0, x1), fmaxf(x2v, x3));
#pragma unroll
    for (int off = 1; off < 16; off <<= 1) m = fmaxf(m, __shfl_xor(m, off));
    float sum = (lane < 10) ? (expf(x0 - m) + expf(x1 - m) + expf(x2v - m) + expf(x3 - m)) : 0.f;
#pragma unroll
    for (int off = 1; off < 16; off <<= 1) sum += __shfl_xor(sum, off);
    if (lane < 10) {
        float lse = m + logf(sum);
        float4* lo = (float4*)(logp + (size_t)node * C_OUT);
        lo[lg] = make_float4(x0 - lse, x1 - lse, x2v - lse, x3 - lse);
    }
}

// ---------------- launcher ----------------
extern "C" void kernel_launch(void* const* d_in, const int* in_sizes, int n_in,
                              void* d_out, int out_size, void* d_ws, size_t ws_size,
                              hipStream_t stream) {
    const float* x  = (const float*)d_in[0];
    const int*   ei = (const int*)d_in[1];
    const float* W1 = (const float*)d_in[2];
    const float* b1 = (const float*)d_in[3];
    const float* W2 = (const float*)d_in[4];
    const float* b2 = (const float*)d_in[5];
    const int N = N_NODES;
    const int E = in_sizes[1] / 2;
    const int* src = ei;
    const int* dst = ei + E;

    float* out_hid  = (float*)d_out;                       // N*128
    float* out_x2   = out_hid + (size_t)N * HID;           // N*40
    float* out_logp = out_x2 + (size_t)N * C_OUT;          // N*40

    char* p = (char*)d_ws;
    auto alloc = [&](size_t bytes) { void* r = (void*)p; p += (bytes + 255) & ~255ull; return r; };
    int*   binCount   = (int*)alloc((size_t)BINS * 4);
    int*   bucketBase = (int*)alloc((size_t)(BINS + 1) * 4);
    int*   binCursor  = (int*)alloc((size_t)BINS * 4);
    int*   offsets    = (int*)alloc((size_t)(N + 1) * 4);
    float* dinv       = (float*)alloc((size_t)N * 4);
    unsigned int*   packed = (unsigned int*)alloc((size_t)E * 4);
    unsigned short* col    = (unsigned short*)alloc((size_t)(E + 64) * 2);
    unsigned short* y1f    = (unsigned short*)alloc((size_t)N * 64 * 2);        // fp8 pairs
    unsigned short* y2b    = (unsigned short*)alloc((size_t)N * C_OUT * 2);     // bf16
    unsigned short* W1bT   = (unsigned short*)alloc((size_t)HID * F_IN * 2);    // bf16 [N][K]

    hipMemsetAsync(binCount, 0, (size_t)BINS * 4, stream);
    k_hist<<<512, 256, 0, stream>>>(dst, E, binCount);
    k_scan_bins<<<1, 256, 0, stream>>>(binCount, bucketBase, binCursor, offsets, E);
    k_partition<<<(E + PCHUNK - 1) / PCHUNK, PTHREADS, 0, stream>>>(src, dst, E, binCursor, packed);
    k_bucket_csr<<<BINS, 1024, 0, stream>>>(packed, bucketBase, offsets, dinv, col, N);
    k_castW1<<<(HID * F_IN + 255) / 256, 256, 0, stream>>>(W1, W1bT);
    k_gemm1<<<(N + 63) / 64, 256, 0, stream>>>(x, W1bT, dinv, y1f, N);
    k_agg1<<<(N + 3) / 4, 256, 0, stream>>>((const uint2*)y1f, col, offsets, dinv, b1, out_hid, N);
    k_gemm2<<<(N + 127) / 128, 256, 0, stream>>>(out_hid, W2, dinv, y2b, N);
    k_agg2<<<(N + 3) / 4, 256, 0, stream>>>((const uint2*)y2b, col, offsets, dinv, b2, out_x2, out_logp, N);
}